// Round 2
// baseline (1606.263 us; speedup 1.0000x reference)
//
#include <hip/hip_runtime.h>
#include <math.h>

// Problem constants
#define BB   64
#define HWP  1024
#define SS   512
#define DD   256
#define TAU_INV (1.0f/0.07f)
#define SIGMA   (1.0f/1024.0f)

// ---- bf16 <-> f32 via bit ops (RNE), avoids __hip_bfloat16 ABI details ----
__device__ __forceinline__ float bf2f(unsigned short u) {
    return __uint_as_float((unsigned)u << 16);
}
__device__ __forceinline__ unsigned short f2bf(float f) {
    unsigned u = __float_as_uint(f);
    u += 0x7FFFu + ((u >> 16) & 1u);
    return (unsigned short)(u >> 16);
}

__device__ __forceinline__ void load4(const float* p, float v[4]) {
    float4 t = *(const float4*)p;
    v[0] = t.x; v[1] = t.y; v[2] = t.z; v[3] = t.w;
}
__device__ __forceinline__ void load4(const unsigned short* p, float v[4]) {
    ushort4 t = *(const ushort4*)p;
    v[0] = bf2f(t.x); v[1] = bf2f(t.y); v[2] = bf2f(t.z); v[3] = bf2f(t.w);
}
__device__ __forceinline__ float load1(const float* p) { return *p; }
__device__ __forceinline__ float load1(const unsigned short* p) { return bf2f(*p); }
__device__ __forceinline__ void store4(float* p, const float v[4]) {
    float4 t; t.x = v[0]; t.y = v[1]; t.z = v[2]; t.w = v[3];
    *(float4*)p = t;
}
__device__ __forceinline__ void store4(unsigned short* p, const float v[4]) {
    ushort4 t; t.x = f2bf(v[0]); t.y = f2bf(v[1]); t.z = f2bf(v[2]); t.w = f2bf(v[3]);
    *(ushort4*)p = t;
}

__global__ void zero_out_k(float* out) { if (threadIdx.x == 0) out[0] = 0.0f; }

// ---------------------------------------------------------------------------
// 64x64-tile GEMM: C[m,n] = sum_k A(m,k)*B(n,k)  (+ epilogue)
//  ACOL=false: element (m,k) at A[m*lda + k];  ACOL=true: at A[k*lda + m]
//  EPI: 0 none, 1 +bias[n], 2 *invm[b*ldc+m]*invn[b*ldc+n]*scale
// ---------------------------------------------------------------------------
template<bool ACOL, bool BCOL, int EPI, typename TA, typename TB, typename TC>
__global__ __launch_bounds__(256) void gemm64(
    const TA* __restrict__ Abase, const TB* __restrict__ Bbase,
    TC* __restrict__ Cbase, int K, int lda, int ldb, int ldc,
    long long strideA, long long strideB, long long strideC,
    const float* __restrict__ bias,
    const float* __restrict__ invm, const float* __restrict__ invn,
    float scale)
{
    const int b = blockIdx.z;
    const TA* A  = Abase + (long long)b * strideA;
    const TB* Bp = Bbase + (long long)b * strideB;
    TC* Cp       = Cbase + (long long)b * strideC;
    const int m0 = blockIdx.x * 64, n0 = blockIdx.y * 64;

    __shared__ float As[16][68];
    __shared__ float Bs[16][68];

    const int tid = threadIdx.x;
    const int tx = tid & 15, ty = tid >> 4;

    float acc[4][4] = {};

    for (int k0 = 0; k0 < K; k0 += 16) {
        float v[4];
        if (ACOL) {
            const int kk = tid >> 4, m4 = tid & 15;
            load4(&A[(long long)(k0 + kk) * lda + m0 + m4 * 4], v);
            *(float4*)&As[kk][m4 * 4] = make_float4(v[0], v[1], v[2], v[3]);
        } else {
            const int m_l = tid >> 2, k4 = tid & 3;
            load4(&A[(long long)(m0 + m_l) * lda + k0 + k4 * 4], v);
            As[k4 * 4 + 0][m_l] = v[0]; As[k4 * 4 + 1][m_l] = v[1];
            As[k4 * 4 + 2][m_l] = v[2]; As[k4 * 4 + 3][m_l] = v[3];
        }
        if (BCOL) {
            const int kk = tid >> 4, n4 = tid & 15;
            load4(&Bp[(long long)(k0 + kk) * ldb + n0 + n4 * 4], v);
            *(float4*)&Bs[kk][n4 * 4] = make_float4(v[0], v[1], v[2], v[3]);
        } else {
            const int n_l = tid >> 2, k4 = tid & 3;
            load4(&Bp[(long long)(n0 + n_l) * ldb + k0 + k4 * 4], v);
            Bs[k4 * 4 + 0][n_l] = v[0]; Bs[k4 * 4 + 1][n_l] = v[1];
            Bs[k4 * 4 + 2][n_l] = v[2]; Bs[k4 * 4 + 3][n_l] = v[3];
        }
        __syncthreads();
        #pragma unroll
        for (int kk = 0; kk < 16; ++kk) {
            float4 a  = *(const float4*)&As[kk][ty * 4];
            float4 bq = *(const float4*)&Bs[kk][tx * 4];
            float av[4]  = {a.x, a.y, a.z, a.w};
            float bv4[4] = {bq.x, bq.y, bq.z, bq.w};
            #pragma unroll
            for (int i = 0; i < 4; ++i)
                #pragma unroll
                for (int j = 0; j < 4; ++j)
                    acc[i][j] += av[i] * bv4[j];
        }
        __syncthreads();
    }

    #pragma unroll
    for (int i = 0; i < 4; ++i) {
        const int m = m0 + ty * 4 + i;
        float vals[4];
        #pragma unroll
        for (int j = 0; j < 4; ++j) {
            const int n = n0 + tx * 4 + j;
            float vv = acc[i][j];
            if (EPI == 1) vv += bias[n];
            if (EPI == 2) vv = vv * invm[b * ldc + m] * invn[b * ldc + n] * scale;
            vals[j] = vv;
        }
        store4(&Cp[(long long)m * ldc + n0 + tx * 4], vals);
    }
}

// mean over rows: dst[b,k] = mean_r src[b,r,k], cols=256
__global__ __launch_bounds__(256) void mean_rows_k(
    const float* __restrict__ src, float* __restrict__ dst, int rows)
{
    const int b = blockIdx.x, k = threadIdx.x;
    const float* p = src + (long long)b * rows * 256 + k;
    float s = 0.f;
    for (int r = 0; r < rows; ++r) s += p[(long long)r * 256];
    dst[b * 256 + k] = s * (1.0f / (float)rows);
}

// y[b,d] = sum_k x[b,k]*W[d,k] + bias[d]
__global__ __launch_bounds__(256) void small_adapter_k(
    const float* __restrict__ x, const float* __restrict__ W,
    const float* __restrict__ bias, float* __restrict__ y)
{
    const int b = blockIdx.x, d = threadIdx.x;
    __shared__ float xs[256];
    xs[d] = x[b * 256 + d];
    __syncthreads();
    const float* w = W + (long long)d * 256;
    float s = bias[d];
    for (int k = 0; k < 256; ++k) s += xs[k] * w[k];
    y[b * 256 + d] = s;
}

// global contrastive loss, single block
__global__ __launch_bounds__(256) void global_loss_k(
    const float* __restrict__ gi, const float* __restrict__ gt,
    float* __restrict__ out)
{
    __shared__ float invI[64], invT[64];
    __shared__ float simm[64][65];
    __shared__ float red[256];
    const int tid = threadIdx.x;

    if (tid < 64) {
        const float* r = gi + tid * 256;
        float s = 0.f;
        for (int k = 0; k < 256; ++k) s += r[k] * r[k];
        invI[tid] = 1.0f / fmaxf(sqrtf(s), 1e-8f);
    } else if (tid < 128) {
        const float* r = gt + (tid - 64) * 256;
        float s = 0.f;
        for (int k = 0; k < 256; ++k) s += r[k] * r[k];
        invT[tid - 64] = 1.0f / fmaxf(sqrtf(s), 1e-8f);
    }
    __syncthreads();

    for (int e = tid; e < 4096; e += 256) {
        const int i = e >> 6, j = e & 63;
        const float* a  = gi + i * 256;
        const float* bq = gt + j * 256;
        float s = 0.f;
        for (int k = 0; k < 256; ++k) s += a[k] * bq[k];
        simm[i][j] = s * invI[i] * invT[j] * TAU_INV;
    }
    __syncthreads();

    float contrib = 0.f;
    if (tid < 64) {
        const int i = tid;
        float m = -1e30f;
        for (int j = 0; j < 64; ++j) m = fmaxf(m, simm[i][j]);
        float s = 0.f;
        for (int j = 0; j < 64; ++j) s += expf(simm[i][j] - m);
        contrib = (m + logf(s)) - simm[i][i];
    } else if (tid < 128) {
        const int j = tid - 64;
        float m = -1e30f;
        for (int i = 0; i < 64; ++i) m = fmaxf(m, simm[i][j]);
        float s = 0.f;
        for (int i = 0; i < 64; ++i) s += expf(simm[i][j] - m);
        contrib = (m + logf(s)) - simm[j][j];
    }
    red[tid] = contrib;
    __syncthreads();
    for (int w = 128; w > 0; w >>= 1) {
        if (tid < w) red[tid] += red[tid + w];
        __syncthreads();
    }
    if (tid == 0) atomicAdd(out, red[0] * (0.5f / 64.0f));
}

// per-(b,s) min/max over p of sim[b,p,s]
template<typename TS>
__global__ __launch_bounds__(256) void minmax_k(
    const TS* __restrict__ sim, float* __restrict__ mn, float* __restrict__ mx)
{
    const int b = blockIdx.x >> 1;
    const int s = ((blockIdx.x & 1) << 8) + threadIdx.x;
    const TS* p = sim + (long long)b * HWP * SS + s;
    float lo = 1e30f, hi = -1e30f;
    for (int r = 0; r < HWP; ++r) {
        float v = load1(p + (long long)r * SS);
        lo = fminf(lo, v); hi = fmaxf(hi, v);
    }
    mn[b * SS + s] = lo;
    mx[b * SS + s] = hi;
}

// in-place: sim -> thresholded min-max-normalized weights
template<typename TS>
__global__ __launch_bounds__(256) void weights_k(
    TS* __restrict__ sim, const float* __restrict__ mn, const float* __restrict__ mx)
{
    const long long n = (long long)BB * HWP * SS;
    for (long long i = (long long)blockIdx.x * 256 + threadIdx.x; i < n;
         i += (long long)gridDim.x * 256) {
        const int idx = (int)(i >> 19) * SS + (int)(i & 511);  // b*S + s
        const float lo = mn[idx], hi = mx[idx];
        float v = (load1(&sim[i]) - lo) / (hi - lo + 1e-8f);
        v = (v < SIGMA) ? 0.0f : v;
        float vv[1] = {v};
        // scalar store (typed)
        if (sizeof(TS) == 4) ((float*)sim)[i] = v;
        else ((unsigned short*)sim)[i] = f2bf(vv[0]);
    }
}

// inv L2 norm of 256-wide rows; one wave per row
__global__ __launch_bounds__(256) void inv_norm_k(
    const float* __restrict__ x, float* __restrict__ inv)
{
    const int row = blockIdx.x * 4 + (threadIdx.x >> 6);
    const int lane = threadIdx.x & 63;
    float4 v = *(const float4*)&x[(long long)row * 256 + lane * 4];
    float s = v.x * v.x + v.y * v.y + v.z * v.z + v.w * v.w;
    #pragma unroll
    for (int o = 32; o > 0; o >>= 1) s += __shfl_xor(s, o);
    if (lane == 0) inv[row] = 1.0f / fmaxf(sqrtf(s), 1e-8f);
}

// row logsumexp - diag over f[b,i,:]
__global__ __launch_bounds__(256) void row_lse_k(
    const float* __restrict__ f, float* __restrict__ out)
{
    const int r = blockIdx.x * 4 + (threadIdx.x >> 6);
    const int lane = threadIdx.x & 63;
    const float* p = f + (long long)r * SS;
    float vals[8];
    float4 v0 = *(const float4*)&p[lane * 8];
    float4 v1 = *(const float4*)&p[lane * 8 + 4];
    vals[0] = v0.x; vals[1] = v0.y; vals[2] = v0.z; vals[3] = v0.w;
    vals[4] = v1.x; vals[5] = v1.y; vals[6] = v1.z; vals[7] = v1.w;
    float m = -1e30f;
    #pragma unroll
    for (int t = 0; t < 8; ++t) m = fmaxf(m, vals[t]);
    #pragma unroll
    for (int o = 32; o > 0; o >>= 1) m = fmaxf(m, __shfl_xor(m, o));
    float s = 0.f;
    #pragma unroll
    for (int t = 0; t < 8; ++t) s += expf(vals[t] - m);
    #pragma unroll
    for (int o = 32; o > 0; o >>= 1) s += __shfl_xor(s, o);
    const float contrib = (m + logf(s)) - p[r & (SS - 1)];
    __shared__ float red[4];
    if (lane == 0) red[threadIdx.x >> 6] = contrib;
    __syncthreads();
    if (threadIdx.x == 0)
        atomicAdd(out, (red[0] + red[1] + red[2] + red[3]) * (0.5f / (64.0f * 512.0f)));
}

// column logsumexp - diag over f[b,:,j]
__global__ __launch_bounds__(256) void col_lse_k(
    const float* __restrict__ f, float* __restrict__ out)
{
    const int b = blockIdx.x >> 1;
    const int j = ((blockIdx.x & 1) << 8) + threadIdx.x;
    const float* p = f + (long long)b * SS * SS + j;
    float m = -1e30f, s = 0.f;
    for (int i = 0; i < SS; ++i) {
        const float x = p[(long long)i * SS];
        const float nm = fmaxf(m, x);
        s = s * expf(m - nm) + expf(x - nm);
        m = nm;
    }
    const float contrib = (m + logf(s)) - p[(long long)j * SS];
    __shared__ float red[256];
    red[threadIdx.x] = contrib;
    __syncthreads();
    for (int w = 128; w > 0; w >>= 1) {
        if (threadIdx.x < w) red[threadIdx.x] += red[threadIdx.x + w];
        __syncthreads();
    }
    if (threadIdx.x == 0) atomicAdd(out, red[0] * (0.5f / (64.0f * 512.0f)));
}

// ---------------------------------------------------------------------------
// Workspace (overlapped):
//  patches  [0, 16.7M floats)      -- dead after step 6; f_sim aliases here
//  tokens   [16.7M, 25.2M)
//  sim      33,554,432 elems of TS -- weights in-place; inv_l/inv_t alias here after step 6
//  lgve     8,388,608 floats       -- stats (means/g/mn/mx) alias here before step 6
// Peak: TS=float -> exactly 256 MiB.  TS=bf16 -> exactly 192 MiB.
// ---------------------------------------------------------------------------
template<typename TS>
static void run_all(const float* img, const float* text, const float* Wv, const float* bv,
                    const float* Wt, const float* bt, float* out, char* wsb, hipStream_t stream)
{
    float* patches = (float*)wsb;
    float* tokens  = patches + 16777216;
    TS*    sim     = (TS*)(tokens + 8388608);
    float* lgve    = (float*)((char*)sim + (size_t)33554432 * sizeof(TS));
    float* mean_pat = lgve;                 // dead before lgve is written
    float* mean_tok = mean_pat + 16384;
    float* g_img    = mean_tok + 16384;
    float* g_txt    = g_img + 16384;
    float* mnv      = g_txt + 16384;
    float* mxv      = mnv + 32768;
    float* inv_l    = (float*)sim;          // weights dead after step 6
    float* inv_t    = inv_l + 32768;
    float* f_sim    = patches;              // patches dead after step 6

    zero_out_k<<<1, 64, 0, stream>>>(out);

    // 1) patches[b,p,d] = sum_c img[b,c,p]*Wv[d,c] + bv[d]
    gemm64<true, false, 1, float, float, float><<<dim3(16, 4, BB), 256, 0, stream>>>(
        img, Wv, patches, 256, HWP, 256, 256,
        (long long)256 * HWP, 0, (long long)HWP * DD, bv, nullptr, nullptr, 0.f);

    // 2) tokens[b,s,d] = sum_k text[b,s,k]*Wt[d,k] + bt[d]
    gemm64<false, false, 1, float, float, float><<<dim3(8, 4, BB), 256, 0, stream>>>(
        text, Wt, tokens, 256, 256, 256, 256,
        (long long)SS * DD, 0, (long long)SS * DD, bt, nullptr, nullptr, 0.f);

    // 3) global embeddings + global loss
    mean_rows_k<<<BB, 256, 0, stream>>>(patches, mean_pat, HWP);
    mean_rows_k<<<BB, 256, 0, stream>>>(tokens, mean_tok, SS);
    small_adapter_k<<<BB, 256, 0, stream>>>(mean_pat, Wv, bv, g_img);
    small_adapter_k<<<BB, 256, 0, stream>>>(mean_tok, Wt, bt, g_txt);
    global_loss_k<<<1, 256, 0, stream>>>(g_img, g_txt, out);

    // 4) sim[b,p,s] = patches[b,p,:] . tokens[b,s,:]
    gemm64<false, false, 0, float, float, TS><<<dim3(16, 8, BB), 256, 0, stream>>>(
        patches, tokens, sim, 256, 256, 256, SS,
        (long long)HWP * DD, (long long)SS * DD, (long long)HWP * SS,
        nullptr, nullptr, nullptr, 0.f);

    // 5) min/max over p, thresholded min-max weights (in-place)
    minmax_k<TS><<<BB * 2, 256, 0, stream>>>(sim, mnv, mxv);
    weights_k<TS><<<16384, 256, 0, stream>>>(sim, mnv, mxv);

    // 6) lgve[b,s,d] = sum_p w[b,p,s]*patches[b,p,d]
    //    (L1 normalization dropped: positive per-row scale cancels in the
    //     subsequent L2 normalization; rows can't be all-zero since the
    //     max-normalized weight ~1.0 >> sigma.)
    gemm64<true, true, 0, TS, float, float><<<dim3(8, 4, BB), 256, 0, stream>>>(
        sim, patches, lgve, HWP, SS, DD, DD,
        (long long)HWP * SS, (long long)HWP * DD, (long long)SS * DD,
        nullptr, nullptr, nullptr, 0.f);

    // 7) inverse L2 norms
    inv_norm_k<<<(BB * SS) / 4, 256, 0, stream>>>(lgve, inv_l);
    inv_norm_k<<<(BB * SS) / 4, 256, 0, stream>>>(tokens, inv_t);

    // 8) f_sim[b,i,j] = cos-sim / tau  (written into patches region)
    gemm64<false, false, 2, float, float, float><<<dim3(8, 8, BB), 256, 0, stream>>>(
        lgve, tokens, f_sim, 256, 256, 256, SS,
        (long long)SS * DD, (long long)SS * DD, (long long)SS * SS,
        nullptr, inv_l, inv_t, TAU_INV);

    // 9) fine-grained symmetric CE
    row_lse_k<<<(BB * SS) / 4, 256, 0, stream>>>(f_sim, out);
    col_lse_k<<<BB * 2, 256, 0, stream>>>(f_sim, out);
}

extern "C" void kernel_launch(void* const* d_in, const int* in_sizes, int n_in,
                              void* d_out, int out_size, void* d_ws, size_t ws_size,
                              hipStream_t stream)
{
    const float* img  = (const float*)d_in[0];  // [B, C, H, W]
    const float* text = (const float*)d_in[1];  // [B, S, D]
    const float* Wv   = (const float*)d_in[2];  // [D, D]
    const float* bv   = (const float*)d_in[3];  // [D]
    const float* Wt   = (const float*)d_in[4];  // [D, D]
    const float* bt   = (const float*)d_in[5];  // [D]
    float* out = (float*)d_out;

    const size_t need_f32 = (size_t)67108864 * 4;  // 256 MiB exactly
    if (ws_size >= need_f32)
        run_all<float>(img, text, Wv, bv, Wt, bt, out, (char*)d_ws, stream);
    else
        run_all<unsigned short>(img, text, Wv, bv, Wt, bt, out, (char*)d_ws, stream);
}

// Round 3
// 869.855 us; speedup vs baseline: 1.8466x; 1.8466x over previous
//
#include <hip/hip_runtime.h>
#include <math.h>

#define BB   64
#define HWP  1024
#define SS   512
#define DD   256
#define TAU_INV (1.0f/0.07f)
#define SIGMA   (1.0f/1024.0f)

typedef unsigned short us;
typedef __attribute__((ext_vector_type(8))) short short8v;
typedef __attribute__((ext_vector_type(8))) unsigned short ushort8v;
typedef __attribute__((ext_vector_type(4))) float floatx4;

__device__ __forceinline__ float bf2f(us u) {
    return __uint_as_float((unsigned)u << 16);
}
__device__ __forceinline__ us f2bf(float f) {
    unsigned u = __float_as_uint(f);
    u += 0x7FFFu + ((u >> 16) & 1u);
    return (us)(u >> 16);
}
__device__ __forceinline__ void split_bf(float v, us& h, us& l) {
    h = f2bf(v);
    l = f2bf(v - bf2f(h));
}

__global__ void zero_out_k(float* out) { if (threadIdx.x == 0) out[0] = 0.0f; }

// =====================  MFMA GEMM  =====================
// C[m,n] = sum_k A(m,k)*B(n,k), 128x128 tile, BK=32, 16x16x32 bf16 MFMA,
// split-bf16 operands (hi+lo) for ~fp32 accuracy: AB ~= AhBh + AhBl + AlBh.
// Operand staging modes:
enum { OPM_F32_ROW = 0,   // fp32 global, (i,k) at p[i*ld+k]  -> split in staging
       OPM_F32_COL = 1,   // fp32 global, (i,k) at p[k*ld+i]  -> split + LDS transpose
       OPM_SPL_ROW = 2,   // bf16 h/l,    (i,k) at p[i*ld+k]
       OPM_SPL_COL = 3,   // bf16 h/l,    (i,k) at p[k*ld+i]  -> LDS transpose
       OPM_B16_COL = 4 }; // bf16 single, (i,k) at p[k*ld+i]  -> LDS transpose
enum { OUT_F32 = 0, OUT_B16 = 1, OUT_SPL = 2 };
// EPI: 0 none, 1 +bias[col], 2 *invm[row]*invn[col]*scale

#define LDSTRIDE 40   // ushorts per LDS row (80 B, 16B-aligned rows, ~2-way banks)

template<int MODE>
__device__ __forceinline__ void stage_tile(
    const char* p0, const char* p1, int ld, int row0, int k0,
    us* ldsH, us* ldsL, int tid)
{
    if constexpr (MODE == OPM_SPL_ROW) {
        const us* ph = (const us*)p0;
        const us* pl = (const us*)p1;
        const int i = tid >> 1, ko = (tid & 1) * 16;
        const long long g = (long long)(row0 + i) * ld + k0 + ko;
        *(ushort8v*)&ldsH[i * LDSTRIDE + ko]     = *(const ushort8v*)&ph[g];
        *(ushort8v*)&ldsH[i * LDSTRIDE + ko + 8] = *(const ushort8v*)&ph[g + 8];
        *(ushort8v*)&ldsL[i * LDSTRIDE + ko]     = *(const ushort8v*)&pl[g];
        *(ushort8v*)&ldsL[i * LDSTRIDE + ko + 8] = *(const ushort8v*)&pl[g + 8];
    } else if constexpr (MODE == OPM_F32_ROW) {
        const float* pf = (const float*)p0;
        const int i = tid >> 1, ko = (tid & 1) * 16;
        const long long g = (long long)(row0 + i) * ld + k0 + ko;
        us h16[16], l16[16];
        #pragma unroll
        for (int c = 0; c < 16; c += 4) {
            float4 v = *(const float4*)&pf[g + c];
            split_bf(v.x, h16[c+0], l16[c+0]); split_bf(v.y, h16[c+1], l16[c+1]);
            split_bf(v.z, h16[c+2], l16[c+2]); split_bf(v.w, h16[c+3], l16[c+3]);
        }
        *(ushort8v*)&ldsH[i * LDSTRIDE + ko]     = *(const ushort8v*)&h16[0];
        *(ushort8v*)&ldsH[i * LDSTRIDE + ko + 8] = *(const ushort8v*)&h16[8];
        *(ushort8v*)&ldsL[i * LDSTRIDE + ko]     = *(const ushort8v*)&l16[0];
        *(ushort8v*)&ldsL[i * LDSTRIDE + ko + 8] = *(const ushort8v*)&l16[8];
    } else if constexpr (MODE == OPM_F32_COL) {
        const float* pf = (const float*)p0;
        const int kk = tid >> 3, io = (tid & 7) * 16;
        const long long g = (long long)(k0 + kk) * ld + row0 + io;
        #pragma unroll
        for (int c = 0; c < 16; c += 4) {
            float4 v = *(const float4*)&pf[g + c];
            us h, l;
            split_bf(v.x, h, l); ldsH[(io+c+0)*LDSTRIDE + kk] = h; ldsL[(io+c+0)*LDSTRIDE + kk] = l;
            split_bf(v.y, h, l); ldsH[(io+c+1)*LDSTRIDE + kk] = h; ldsL[(io+c+1)*LDSTRIDE + kk] = l;
            split_bf(v.z, h, l); ldsH[(io+c+2)*LDSTRIDE + kk] = h; ldsL[(io+c+2)*LDSTRIDE + kk] = l;
            split_bf(v.w, h, l); ldsH[(io+c+3)*LDSTRIDE + kk] = h; ldsL[(io+c+3)*LDSTRIDE + kk] = l;
        }
    } else if constexpr (MODE == OPM_B16_COL) {
        const us* ph = (const us*)p0;
        const int kk = tid >> 3, io = (tid & 7) * 16;
        const long long g = (long long)(k0 + kk) * ld + row0 + io;
        ushort8v a = *(const ushort8v*)&ph[g];
        ushort8v b = *(const ushort8v*)&ph[g + 8];
        #pragma unroll
        for (int j = 0; j < 8; ++j) {
            ldsH[(io + j)     * LDSTRIDE + kk] = a[j];
            ldsH[(io + j + 8) * LDSTRIDE + kk] = b[j];
        }
    } else if constexpr (MODE == OPM_SPL_COL) {
        const us* ph = (const us*)p0;
        const us* pl = (const us*)p1;
        const int kk = tid >> 3, io = (tid & 7) * 16;
        const long long g = (long long)(k0 + kk) * ld + row0 + io;
        ushort8v a = *(const ushort8v*)&ph[g];
        ushort8v b = *(const ushort8v*)&ph[g + 8];
        ushort8v c = *(const ushort8v*)&pl[g];
        ushort8v d = *(const ushort8v*)&pl[g + 8];
        #pragma unroll
        for (int j = 0; j < 8; ++j) {
            ldsH[(io + j)     * LDSTRIDE + kk] = a[j];
            ldsH[(io + j + 8) * LDSTRIDE + kk] = b[j];
            ldsL[(io + j)     * LDSTRIDE + kk] = c[j];
            ldsL[(io + j + 8) * LDSTRIDE + kk] = d[j];
        }
    }
}

template<int AMODE, int BMODE, int OMODE, int EPI>
__global__ __launch_bounds__(256) void mfma_gemm(
    const void* A0, const void* A1, const void* B0, const void* B1,
    void* C0, void* C1,
    int M, int N, int K, int lda, int ldb, int ldc,
    long long sA, long long sB, long long sC,   // byte strides per batch
    const float* __restrict__ bias, const float* __restrict__ invm,
    const float* __restrict__ invn, float scale)
{
    constexpr bool ASPL = (AMODE != OPM_B16_COL);
    constexpr bool BSPL = (BMODE != OPM_B16_COL);
    constexpr int ASZ = 128 * LDSTRIDE;
    __shared__ __align__(16) us Ah[ASZ];
    __shared__ __align__(16) us Al[ASPL ? ASZ : 8];
    __shared__ __align__(16) us Bh[ASZ];
    __shared__ __align__(16) us Bl[BSPL ? ASZ : 8];

    const int tid = threadIdx.x;
    const int w = tid >> 6, lane = tid & 63;
    const int quad = lane >> 4, l16 = lane & 15;
    const int m0 = blockIdx.x * 128, n0 = blockIdx.y * 128;
    const int b = blockIdx.z;

    const char* Ab0 = (const char*)A0 + (long long)b * sA;
    const char* Ab1 = A1 ? (const char*)A1 + (long long)b * sA : nullptr;
    const char* Bb0 = (const char*)B0 + (long long)b * sB;
    const char* Bb1 = B1 ? (const char*)B1 + (long long)b * sB : nullptr;

    floatx4 acc[2][8];
    #pragma unroll
    for (int mi = 0; mi < 2; ++mi)
        #pragma unroll
        for (int ni = 0; ni < 8; ++ni)
            acc[mi][ni] = (floatx4){0.f, 0.f, 0.f, 0.f};

    for (int k0 = 0; k0 < K; k0 += 32) {
        stage_tile<AMODE>(Ab0, Ab1, lda, m0, k0, Ah, Al, tid);
        stage_tile<BMODE>(Bb0, Bb1, ldb, n0, k0, Bh, Bl, tid);
        __syncthreads();

        short8v ah[2], al[2], bh[8], bl[8];
        #pragma unroll
        for (int mi = 0; mi < 2; ++mi) {
            const int r = (32 * w + 16 * mi + l16) * LDSTRIDE + quad * 8;
            ah[mi] = *(const short8v*)&Ah[r];
            if constexpr (ASPL) al[mi] = *(const short8v*)&Al[r];
        }
        #pragma unroll
        for (int ni = 0; ni < 8; ++ni) {
            const int r = (16 * ni + l16) * LDSTRIDE + quad * 8;
            bh[ni] = *(const short8v*)&Bh[r];
            if constexpr (BSPL) bl[ni] = *(const short8v*)&Bl[r];
        }
        #pragma unroll
        for (int mi = 0; mi < 2; ++mi)
            #pragma unroll
            for (int ni = 0; ni < 8; ++ni) {
                acc[mi][ni] = __builtin_amdgcn_mfma_f32_16x16x32_bf16(ah[mi], bh[ni], acc[mi][ni], 0, 0, 0);
                if constexpr (BSPL)
                    acc[mi][ni] = __builtin_amdgcn_mfma_f32_16x16x32_bf16(ah[mi], bl[ni], acc[mi][ni], 0, 0, 0);
                if constexpr (ASPL)
                    acc[mi][ni] = __builtin_amdgcn_mfma_f32_16x16x32_bf16(al[mi], bh[ni], acc[mi][ni], 0, 0, 0);
            }
        __syncthreads();
    }

    char* Cb0 = (char*)C0 + (long long)b * sC;
    char* Cb1 = C1 ? (char*)C1 + (long long)b * sC : nullptr;
    #pragma unroll
    for (int mi = 0; mi < 2; ++mi)
        #pragma unroll
        for (int ni = 0; ni < 8; ++ni)
            #pragma unroll
            for (int r = 0; r < 4; ++r) {
                const int row = m0 + 32 * w + 16 * mi + quad * 4 + r;
                const int col = n0 + 16 * ni + l16;
                float v = acc[mi][ni][r];
                if constexpr (EPI == 1) v += bias[col];
                if constexpr (EPI == 2) v *= invm[b * M + row] * invn[b * N + col] * scale;
                const long long idx = (long long)row * ldc + col;
                if constexpr (OMODE == OUT_F32) {
                    ((float*)Cb0)[idx] = v;
                } else if constexpr (OMODE == OUT_B16) {
                    ((us*)Cb0)[idx] = f2bf(v);
                } else {
                    us h, l; split_bf(v, h, l);
                    ((us*)Cb0)[idx] = h;
                    ((us*)Cb1)[idx] = l;
                }
            }
}

// =====================  small kernels  =====================

// Wv/Wt -> split bf16 (65536 elems each); grid 256
__global__ __launch_bounds__(256) void convert_w_k(
    const float* Wv, const float* Wt, us* Wvh, us* Wvl, us* Wth, us* Wtl)
{
    const int i = blockIdx.x * 256 + threadIdx.x;
    split_bf(Wv[i], Wvh[i], Wvl[i]);
    split_bf(Wt[i], Wth[i], Wtl[i]);
}

// mean over hw of img[b,c,:]; one wave per (b,c) row; grid 4096
__global__ __launch_bounds__(256) void mean_img_k(
    const float* __restrict__ img, float* __restrict__ mimg)
{
    const int row = blockIdx.x * 4 + (threadIdx.x >> 6);
    const int lane = threadIdx.x & 63;
    const float* p = img + (long long)row * 1024;
    float s = 0.f;
    #pragma unroll
    for (int c = 0; c < 4; ++c) {
        float4 v = *(const float4*)&p[(c * 64 + lane) * 4];
        s += v.x + v.y + v.z + v.w;
    }
    #pragma unroll
    for (int o = 32; o > 0; o >>= 1) s += __shfl_xor(s, o);
    if (lane == 0) mimg[row] = s * (1.0f / 1024.0f);
}

// mean over s of text[b,s,k] stage 1: grid (64, 8)
__global__ __launch_bounds__(256) void mean_text_s1(
    const float* __restrict__ text, float* __restrict__ part)
{
    const int b = blockIdx.x, ch = blockIdx.y, k = threadIdx.x;
    const float* p = text + ((long long)b * 512 + ch * 64) * 256 + k;
    float s = 0.f;
    for (int r = 0; r < 64; ++r) s += p[r * 256];
    part[(b * 8 + ch) * 256 + k] = s;
}
__global__ __launch_bounds__(256) void mean_text_s2(
    const float* __restrict__ part, float* __restrict__ mt)
{
    const int b = blockIdx.x, k = threadIdx.x;
    float s = 0.f;
    for (int c = 0; c < 8; ++c) s += part[(b * 8 + c) * 256 + k];
    mt[b * 256 + k] = s * (1.0f / 512.0f);
}

// y[b,d] = sum_k x[b,k]*W[d,k] + bias[d]
__global__ __launch_bounds__(256) void small_adapter_k(
    const float* __restrict__ x, const float* __restrict__ W,
    const float* __restrict__ bias, float* __restrict__ y)
{
    const int b = blockIdx.x, d = threadIdx.x;
    __shared__ float xs[256];
    xs[d] = x[b * 256 + d];
    __syncthreads();
    const float* w = W + (long long)d * 256;
    float s = bias[d];
    for (int k = 0; k < 256; ++k) s += xs[k] * w[k];
    y[b * 256 + d] = s;
}

__global__ __launch_bounds__(256) void global_loss_k(
    const float* __restrict__ gi, const float* __restrict__ gt,
    float* __restrict__ out)
{
    __shared__ float invI[64], invT[64];
    __shared__ float simm[64][65];
    __shared__ float red[256];
    const int tid = threadIdx.x;
    if (tid < 64) {
        const float* r = gi + tid * 256;
        float s = 0.f;
        for (int k = 0; k < 256; ++k) s += r[k] * r[k];
        invI[tid] = 1.0f / fmaxf(sqrtf(s), 1e-8f);
    } else if (tid < 128) {
        const float* r = gt + (tid - 64) * 256;
        float s = 0.f;
        for (int k = 0; k < 256; ++k) s += r[k] * r[k];
        invT[tid - 64] = 1.0f / fmaxf(sqrtf(s), 1e-8f);
    }
    __syncthreads();
    for (int e = tid; e < 4096; e += 256) {
        const int i = e >> 6, j = e & 63;
        const float* a = gi + i * 256;
        const float* bq = gt + j * 256;
        float s = 0.f;
        for (int k = 0; k < 256; ++k) s += a[k] * bq[k];
        simm[i][j] = s * invI[i] * invT[j] * TAU_INV;
    }
    __syncthreads();
    float contrib = 0.f;
    if (tid < 64) {
        const int i = tid;
        float m = -1e30f;
        for (int j = 0; j < 64; ++j) m = fmaxf(m, simm[i][j]);
        float s = 0.f;
        for (int j = 0; j < 64; ++j) s += expf(simm[i][j] - m);
        contrib = (m + logf(s)) - simm[i][i];
    } else if (tid < 128) {
        const int j = tid - 64;
        float m = -1e30f;
        for (int i = 0; i < 64; ++i) m = fmaxf(m, simm[i][j]);
        float s = 0.f;
        for (int i = 0; i < 64; ++i) s += expf(simm[i][j] - m);
        contrib = (m + logf(s)) - simm[j][j];
    }
    red[tid] = contrib;
    __syncthreads();
    for (int w = 128; w > 0; w >>= 1) {
        if (tid < w) red[tid] += red[tid + w];
        __syncthreads();
    }
    if (tid == 0) atomicAdd(out, red[0] * (0.5f / 64.0f));
}

// minmax over p of bf16 sim, stage1: grid (128, 8); stage2: grid 128
__global__ __launch_bounds__(256) void minmax_s1(
    const us* __restrict__ simW, float* __restrict__ mnp, float* __restrict__ mxp)
{
    const int bx = blockIdx.x;
    const int b = bx >> 1, s = ((bx & 1) << 8) + threadIdx.x;
    const int ch = blockIdx.y;
    const us* p = simW + ((long long)b * 1024 + ch * 128) * 512 + s;
    float lo = 1e30f, hi = -1e30f;
    for (int r = 0; r < 128; ++r) {
        const float v = bf2f(p[(long long)r * 512]);
        lo = fminf(lo, v); hi = fmaxf(hi, v);
    }
    mnp[((long long)b * 8 + ch) * 512 + s] = lo;
    mxp[((long long)b * 8 + ch) * 512 + s] = hi;
}
__global__ __launch_bounds__(256) void minmax_s2(
    const float* __restrict__ mnp, const float* __restrict__ mxp,
    float* __restrict__ mn, float* __restrict__ mx)
{
    const int bx = blockIdx.x;
    const int b = bx >> 1, s = ((bx & 1) << 8) + threadIdx.x;
    float lo = 1e30f, hi = -1e30f;
    for (int c = 0; c < 8; ++c) {
        lo = fminf(lo, mnp[((long long)b * 8 + c) * 512 + s]);
        hi = fmaxf(hi, mxp[((long long)b * 8 + c) * 512 + s]);
    }
    mn[b * 512 + s] = lo;
    mx[b * 512 + s] = hi;
}

// in-place bf16: sim -> thresholded min-max weights; grid 4096
__global__ __launch_bounds__(256) void weights_bf_k(
    us* __restrict__ simW, const float* __restrict__ mn, const float* __restrict__ mx)
{
    const long long n8 = (long long)BB * HWP * SS / 8;
    for (long long i8 = (long long)blockIdx.x * 256 + threadIdx.x; i8 < n8;
         i8 += (long long)gridDim.x * 256) {
        const long long i = i8 * 8;
        const int b = (int)(i >> 19), s0 = (int)(i & 511);
        ushort8v v = *(const ushort8v*)&simW[i];
        const float* mnb = mn + b * 512;
        const float* mxb = mx + b * 512;
        ushort8v o;
        #pragma unroll
        for (int j = 0; j < 8; ++j) {
            const float lo = mnb[s0 + j], hi = mxb[s0 + j];
            const float w = (bf2f(v[j]) - lo) / (hi - lo + 1e-8f);
            o[j] = (w < SIGMA) ? (us)0 : f2bf(w);
        }
        *(ushort8v*)&simW[i] = o;
    }
}

// inv L2 norm of 256-wide split-bf16 rows; one wave per row; grid rows/4
__global__ __launch_bounds__(256) void inv_norm_spl_k(
    const us* __restrict__ xh, const us* __restrict__ xl, float* __restrict__ inv)
{
    const int row = blockIdx.x * 4 + (threadIdx.x >> 6);
    const int lane = threadIdx.x & 63;
    ushort4 h = *(const ushort4*)&xh[(long long)row * 256 + lane * 4];
    ushort4 l = *(const ushort4*)&xl[(long long)row * 256 + lane * 4];
    const float x0 = bf2f(h.x) + bf2f(l.x), x1 = bf2f(h.y) + bf2f(l.y);
    const float x2 = bf2f(h.z) + bf2f(l.z), x3 = bf2f(h.w) + bf2f(l.w);
    float s = x0 * x0 + x1 * x1 + x2 * x2 + x3 * x3;
    #pragma unroll
    for (int o = 32; o > 0; o >>= 1) s += __shfl_xor(s, o);
    if (lane == 0) inv[row] = 1.0f / fmaxf(sqrtf(s), 1e-8f);
}

// row logsumexp - diag over f[b,i,:]; grid 8192
__global__ __launch_bounds__(256) void row_lse_k(
    const float* __restrict__ f, float* __restrict__ out)
{
    const int r = blockIdx.x * 4 + (threadIdx.x >> 6);
    const int lane = threadIdx.x & 63;
    const float* p = f + (long long)r * SS;
    float vals[8];
    float4 v0 = *(const float4*)&p[lane * 8];
    float4 v1 = *(const float4*)&p[lane * 8 + 4];
    vals[0] = v0.x; vals[1] = v0.y; vals[2] = v0.z; vals[3] = v0.w;
    vals[4] = v1.x; vals[5] = v1.y; vals[6] = v1.z; vals[7] = v1.w;
    float m = -1e30f;
    #pragma unroll
    for (int t = 0; t < 8; ++t) m = fmaxf(m, vals[t]);
    #pragma unroll
    for (int o = 32; o > 0; o >>= 1) m = fmaxf(m, __shfl_xor(m, o));
    float s = 0.f;
    #pragma unroll
    for (int t = 0; t < 8; ++t) s += expf(vals[t] - m);
    #pragma unroll
    for (int o = 32; o > 0; o >>= 1) s += __shfl_xor(s, o);
    const float contrib = (m + logf(s)) - p[r & (SS - 1)];
    __shared__ float red[4];
    if (lane == 0) red[threadIdx.x >> 6] = contrib;
    __syncthreads();
    if (threadIdx.x == 0)
        atomicAdd(out, (red[0] + red[1] + red[2] + red[3]) * (0.5f / (64.0f * 512.0f)));
}

// column logsumexp - diag; grid 128
__global__ __launch_bounds__(256) void col_lse_k(
    const float* __restrict__ f, float* __restrict__ out)
{
    const int b = blockIdx.x >> 1;
    const int j = ((blockIdx.x & 1) << 8) + threadIdx.x;
    const float* p = f + (long long)b * SS * SS + j;
    float m = -1e30f, s = 0.f;
    for (int i = 0; i < SS; ++i) {
        const float x = p[(long long)i * SS];
        const float nm = fmaxf(m, x);
        s = s * expf(m - nm) + expf(x - nm);
        m = nm;
    }
    const float contrib = (m + logf(s)) - p[(long long)j * SS];
    __shared__ float red[256];
    red[threadIdx.x] = contrib;
    __syncthreads();
    for (int w = 128; w > 0; w >>= 1) {
        if (threadIdx.x < w) red[threadIdx.x] += red[threadIdx.x + w];
        __syncthreads();
    }
    if (threadIdx.x == 0) atomicAdd(out, red[0] * (0.5f / (64.0f * 512.0f)));
}

extern "C" void kernel_launch(void* const* d_in, const int* in_sizes, int n_in,
                              void* d_out, int out_size, void* d_ws, size_t ws_size,
                              hipStream_t stream)
{
    const float* img  = (const float*)d_in[0];  // [B, C, H, W] = [64,256,32,32]
    const float* text = (const float*)d_in[1];  // [B, S, D]
    const float* Wv   = (const float*)d_in[2];
    const float* bv   = (const float*)d_in[3];
    const float* Wt   = (const float*)d_in[4];
    const float* bt   = (const float*)d_in[5];
    float* out = (float*)d_out;
    char* ws = (char*)d_ws;

    // ---- workspace map (bytes) ----
    us* patches_h = (us*)(ws + 0);            // 33,554,432 B
    us* patches_l = (us*)(ws + 33554432);
    us* tokens_h  = (us*)(ws + 67108864);     // 16,777,216 B
    us* tokens_l  = (us*)(ws + 83886080);
    us* simW      = (us*)(ws + 100663296);    // 67,108,864 B (bf16 sim/weights)
    float* f_sim  = (float*)(ws + 100663296); // reuse after GEMM6 (67,108,864 B f32)
    us* lgve_h    = (us*)(ws + 167772160);
    us* lgve_l    = (us*)(ws + 184549376);
    char* st = ws + 201326592;                // stats block
    float* mean_img  = (float*)(st + 0);
    float* mean_text = (float*)(st + 65536);
    float* mean_pat  = (float*)(st + 131072);
    float* mean_tok  = (float*)(st + 196608);
    float* g_img     = (float*)(st + 262144);
    float* g_txt     = (float*)(st + 327680);
    float* textpart  = (float*)(st + 393216);
    float* mnp       = (float*)(st + 917504);
    float* mxp       = (float*)(st + 1966080);
    float* mnv       = (float*)(st + 3014656);
    float* mxv       = (float*)(st + 3145728);
    float* inv_l     = (float*)(st + 3276800);
    float* inv_t     = (float*)(st + 3407872);
    us* Wvh = (us*)(st + 3538944);
    us* Wvl = (us*)(st + 3670016);
    us* Wth = (us*)(st + 3801088);
    us* Wtl = (us*)(st + 3932160);

    zero_out_k<<<1, 64, 0, stream>>>(out);
    convert_w_k<<<256, 256, 0, stream>>>(Wv, Wt, Wvh, Wvl, Wth, Wtl);

    // Global path (mean commutes with linear): means from raw inputs.
    mean_img_k<<<4096, 256, 0, stream>>>(img, mean_img);
    mean_text_s1<<<dim3(64, 8), 256, 0, stream>>>(text, textpart);
    mean_text_s2<<<64, 256, 0, stream>>>(textpart, mean_text);
    small_adapter_k<<<BB, 256, 0, stream>>>(mean_img, Wv, bv, mean_pat);
    small_adapter_k<<<BB, 256, 0, stream>>>(mean_pat, Wv, bv, g_img);
    small_adapter_k<<<BB, 256, 0, stream>>>(mean_text, Wt, bt, mean_tok);
    small_adapter_k<<<BB, 256, 0, stream>>>(mean_tok, Wt, bt, g_txt);
    global_loss_k<<<1, 256, 0, stream>>>(g_img, g_txt, out);

    // G1: patches[p,d] = sum_c img[c,p]*Wv[d,c] + bv  (A fp32 K-major)
    mfma_gemm<OPM_F32_COL, OPM_SPL_ROW, OUT_SPL, 1><<<dim3(8, 2, BB), 256, 0, stream>>>(
        img, nullptr, Wvh, Wvl, patches_h, patches_l,
        1024, 256, 256, 1024, 256, 256,
        1048576LL, 0LL, 524288LL, bv, nullptr, nullptr, 0.f);

    // G2: tokens[s,d] = sum_k text[s,k]*Wt[d,k] + bt
    mfma_gemm<OPM_F32_ROW, OPM_SPL_ROW, OUT_SPL, 1><<<dim3(4, 2, BB), 256, 0, stream>>>(
        text, nullptr, Wth, Wtl, tokens_h, tokens_l,
        512, 256, 256, 256, 256, 256,
        524288LL, 0LL, 262144LL, bt, nullptr, nullptr, 0.f);

    // G4: sim[p,s] = patches[p,:].tokens[s,:]  -> bf16
    mfma_gemm<OPM_SPL_ROW, OPM_SPL_ROW, OUT_B16, 0><<<dim3(8, 4, BB), 256, 0, stream>>>(
        patches_h, patches_l, tokens_h, tokens_l, simW, nullptr,
        1024, 512, 256, 256, 256, 512,
        524288LL, 262144LL, 1048576LL, nullptr, nullptr, nullptr, 0.f);

    // min-max + threshold weights (in-place bf16)
    minmax_s1<<<dim3(128, 8), 256, 0, stream>>>(simW, mnp, mxp);
    minmax_s2<<<128, 256, 0, stream>>>(mnp, mxp, mnv, mxv);
    weights_bf_k<<<4096, 256, 0, stream>>>(simW, mnv, mxv);

    // G6: lgve[s,d] = sum_p w[p,s]*patches[p,d]  (A bf16 K-major, B split K-major)
    //     L1 norm dropped: positive row scale cancels in later L2 norm (verified R2).
    mfma_gemm<OPM_B16_COL, OPM_SPL_COL, OUT_SPL, 0><<<dim3(4, 2, BB), 256, 0, stream>>>(
        simW, nullptr, patches_h, patches_l, lgve_h, lgve_l,
        512, 256, 1024, 512, 256, 256,
        1048576LL, 524288LL, 262144LL, nullptr, nullptr, nullptr, 0.f);

    // inverse L2 norms
    inv_norm_spl_k<<<8192, 256, 0, stream>>>(lgve_h, lgve_l, inv_l);
    inv_norm_spl_k<<<8192, 256, 0, stream>>>(tokens_h, tokens_l, inv_t);

    // G8: f_sim[i,j] = lgve[i,:].tokens[j,:] * invm*invn/tau  -> fp32
    mfma_gemm<OPM_SPL_ROW, OPM_SPL_ROW, OUT_F32, 2><<<dim3(4, 4, BB), 256, 0, stream>>>(
        lgve_h, lgve_l, tokens_h, tokens_l, f_sim, nullptr,
        512, 512, 256, 256, 256, 512,
        262144LL, 262144LL, 1048576LL, nullptr, inv_l, inv_t, TAU_INV);

    // fine-grained symmetric CE
    row_lse_k<<<8192, 256, 0, stream>>>(f_sim, out);
    col_lse_k<<<128, 256, 0, stream>>>(f_sim, out);
}

// Round 4
// 734.481 us; speedup vs baseline: 2.1869x; 1.1843x over previous
//
#include <hip/hip_runtime.h>
#include <math.h>

#define BB   64
#define HWP  1024
#define SS   512
#define DD   256
#define TAU_INV (1.0f/0.07f)
#define SIGMA   (1.0f/1024.0f)

typedef unsigned short us;
typedef __attribute__((ext_vector_type(8))) short short8v;
typedef __attribute__((ext_vector_type(8))) unsigned short ushort8v;
typedef __attribute__((ext_vector_type(4))) float floatx4;

__device__ __forceinline__ float bf2f(us u) {
    return __uint_as_float((unsigned)u << 16);
}
__device__ __forceinline__ us f2bf(float f) {
    unsigned u = __float_as_uint(f);
    u += 0x7FFFu + ((u >> 16) & 1u);
    return (us)(u >> 16);
}
__device__ __forceinline__ void split_bf(float v, us& h, us& l) {
    h = f2bf(v);
    l = f2bf(v - bf2f(h));
}

__global__ void zero_out_k(float* out) { if (threadIdx.x == 0) out[0] = 0.0f; }

// =====================  MFMA GEMM  =====================
// C[m,n] = sum_k A(m,k)*B(n,k), 128x128 tile, BK=32, 16x16x32 bf16 MFMA,
// split-bf16 operands (hi+lo): AB ~= AhBh + AhBl + AlBh.
enum { OPM_F32_ROW = 0, OPM_F32_COL = 1, OPM_SPL_ROW = 2, OPM_SPL_COL = 3,
       OPM_B16_COL = 4 };
enum { OUT_F32 = 0, OUT_B16 = 1, OUT_SPL = 2 };

#define LDSTRIDE 40

template<int MODE>
__device__ __forceinline__ void stage_tile(
    const char* p0, const char* p1, int ld, int row0, int k0,
    us* ldsH, us* ldsL, int tid)
{
    if constexpr (MODE == OPM_SPL_ROW) {
        const us* ph = (const us*)p0;
        const us* pl = (const us*)p1;
        const int i = tid >> 1, ko = (tid & 1) * 16;
        const long long g = (long long)(row0 + i) * ld + k0 + ko;
        *(ushort8v*)&ldsH[i * LDSTRIDE + ko]     = *(const ushort8v*)&ph[g];
        *(ushort8v*)&ldsH[i * LDSTRIDE + ko + 8] = *(const ushort8v*)&ph[g + 8];
        *(ushort8v*)&ldsL[i * LDSTRIDE + ko]     = *(const ushort8v*)&pl[g];
        *(ushort8v*)&ldsL[i * LDSTRIDE + ko + 8] = *(const ushort8v*)&pl[g + 8];
    } else if constexpr (MODE == OPM_F32_ROW) {
        const float* pf = (const float*)p0;
        const int i = tid >> 1, ko = (tid & 1) * 16;
        const long long g = (long long)(row0 + i) * ld + k0 + ko;
        us h16[16], l16[16];
        #pragma unroll
        for (int c = 0; c < 16; c += 4) {
            float4 v = *(const float4*)&pf[g + c];
            split_bf(v.x, h16[c+0], l16[c+0]); split_bf(v.y, h16[c+1], l16[c+1]);
            split_bf(v.z, h16[c+2], l16[c+2]); split_bf(v.w, h16[c+3], l16[c+3]);
        }
        *(ushort8v*)&ldsH[i * LDSTRIDE + ko]     = *(const ushort8v*)&h16[0];
        *(ushort8v*)&ldsH[i * LDSTRIDE + ko + 8] = *(const ushort8v*)&h16[8];
        *(ushort8v*)&ldsL[i * LDSTRIDE + ko]     = *(const ushort8v*)&l16[0];
        *(ushort8v*)&ldsL[i * LDSTRIDE + ko + 8] = *(const ushort8v*)&l16[8];
    } else if constexpr (MODE == OPM_F32_COL) {
        const float* pf = (const float*)p0;
        const int kk = tid >> 3, io = (tid & 7) * 16;
        const long long g = (long long)(k0 + kk) * ld + row0 + io;
        #pragma unroll
        for (int c = 0; c < 16; c += 4) {
            float4 v = *(const float4*)&pf[g + c];
            us h, l;
            split_bf(v.x, h, l); ldsH[(io+c+0)*LDSTRIDE + kk] = h; ldsL[(io+c+0)*LDSTRIDE + kk] = l;
            split_bf(v.y, h, l); ldsH[(io+c+1)*LDSTRIDE + kk] = h; ldsL[(io+c+1)*LDSTRIDE + kk] = l;
            split_bf(v.z, h, l); ldsH[(io+c+2)*LDSTRIDE + kk] = h; ldsL[(io+c+2)*LDSTRIDE + kk] = l;
            split_bf(v.w, h, l); ldsH[(io+c+3)*LDSTRIDE + kk] = h; ldsL[(io+c+3)*LDSTRIDE + kk] = l;
        }
    } else if constexpr (MODE == OPM_B16_COL) {
        const us* ph = (const us*)p0;
        const int kk = tid >> 3, io = (tid & 7) * 16;
        const long long g = (long long)(k0 + kk) * ld + row0 + io;
        ushort8v a = *(const ushort8v*)&ph[g];
        ushort8v b = *(const ushort8v*)&ph[g + 8];
        #pragma unroll
        for (int j = 0; j < 8; ++j) {
            ldsH[(io + j)     * LDSTRIDE + kk] = a[j];
            ldsH[(io + j + 8) * LDSTRIDE + kk] = b[j];
        }
    } else if constexpr (MODE == OPM_SPL_COL) {
        const us* ph = (const us*)p0;
        const us* pl = (const us*)p1;
        const int kk = tid >> 3, io = (tid & 7) * 16;
        const long long g = (long long)(k0 + kk) * ld + row0 + io;
        ushort8v a = *(const ushort8v*)&ph[g];
        ushort8v b = *(const ushort8v*)&ph[g + 8];
        ushort8v c = *(const ushort8v*)&pl[g];
        ushort8v d = *(const ushort8v*)&pl[g + 8];
        #pragma unroll
        for (int j = 0; j < 8; ++j) {
            ldsH[(io + j)     * LDSTRIDE + kk] = a[j];
            ldsH[(io + j + 8) * LDSTRIDE + kk] = b[j];
            ldsL[(io + j)     * LDSTRIDE + kk] = c[j];
            ldsL[(io + j + 8) * LDSTRIDE + kk] = d[j];
        }
    }
}

template<int AMODE, int BMODE, int OMODE, int EPI>
__global__ __launch_bounds__(256) void mfma_gemm(
    const void* A0, const void* A1, const void* B0, const void* B1,
    void* C0, void* C1,
    int M, int N, int K, int lda, int ldb, int ldc,
    long long sA, long long sB, long long sC,
    const float* __restrict__ bias, const float* __restrict__ invm,
    const float* __restrict__ invn, float scale)
{
    constexpr bool ASPL = (AMODE != OPM_B16_COL);
    constexpr bool BSPL = (BMODE != OPM_B16_COL);
    constexpr int ASZ = 128 * LDSTRIDE;
    __shared__ __align__(16) us Ah[ASZ];
    __shared__ __align__(16) us Al[ASPL ? ASZ : 8];
    __shared__ __align__(16) us Bh[ASZ];
    __shared__ __align__(16) us Bl[BSPL ? ASZ : 8];

    const int tid = threadIdx.x;
    const int w = tid >> 6, lane = tid & 63;
    const int quad = lane >> 4, l16 = lane & 15;
    const int m0 = blockIdx.x * 128, n0 = blockIdx.y * 128;
    const int b = blockIdx.z;

    const char* Ab0 = (const char*)A0 + (long long)b * sA;
    const char* Ab1 = A1 ? (const char*)A1 + (long long)b * sA : nullptr;
    const char* Bb0 = (const char*)B0 + (long long)b * sB;
    const char* Bb1 = B1 ? (const char*)B1 + (long long)b * sB : nullptr;

    floatx4 acc[2][8];
    #pragma unroll
    for (int mi = 0; mi < 2; ++mi)
        #pragma unroll
        for (int ni = 0; ni < 8; ++ni)
            acc[mi][ni] = (floatx4){0.f, 0.f, 0.f, 0.f};

    for (int k0 = 0; k0 < K; k0 += 32) {
        stage_tile<AMODE>(Ab0, Ab1, lda, m0, k0, Ah, Al, tid);
        stage_tile<BMODE>(Bb0, Bb1, ldb, n0, k0, Bh, Bl, tid);
        __syncthreads();

        short8v ah[2], al[2], bh[8], bl[8];
        #pragma unroll
        for (int mi = 0; mi < 2; ++mi) {
            const int r = (32 * w + 16 * mi + l16) * LDSTRIDE + quad * 8;
            ah[mi] = *(const short8v*)&Ah[r];
            if constexpr (ASPL) al[mi] = *(const short8v*)&Al[r];
        }
        #pragma unroll
        for (int ni = 0; ni < 8; ++ni) {
            const int r = (16 * ni + l16) * LDSTRIDE + quad * 8;
            bh[ni] = *(const short8v*)&Bh[r];
            if constexpr (BSPL) bl[ni] = *(const short8v*)&Bl[r];
        }
        #pragma unroll
        for (int mi = 0; mi < 2; ++mi)
            #pragma unroll
            for (int ni = 0; ni < 8; ++ni) {
                acc[mi][ni] = __builtin_amdgcn_mfma_f32_16x16x32_bf16(ah[mi], bh[ni], acc[mi][ni], 0, 0, 0);
                if constexpr (BSPL)
                    acc[mi][ni] = __builtin_amdgcn_mfma_f32_16x16x32_bf16(ah[mi], bl[ni], acc[mi][ni], 0, 0, 0);
                if constexpr (ASPL)
                    acc[mi][ni] = __builtin_amdgcn_mfma_f32_16x16x32_bf16(al[mi], bh[ni], acc[mi][ni], 0, 0, 0);
            }
        __syncthreads();
    }

    char* Cb0 = (char*)C0 + (long long)b * sC;
    char* Cb1 = C1 ? (char*)C1 + (long long)b * sC : nullptr;
    #pragma unroll
    for (int mi = 0; mi < 2; ++mi)
        #pragma unroll
        for (int ni = 0; ni < 8; ++ni)
            #pragma unroll
            for (int r = 0; r < 4; ++r) {
                const int row = m0 + 32 * w + 16 * mi + quad * 4 + r;
                const int col = n0 + 16 * ni + l16;
                float v = acc[mi][ni][r];
                if constexpr (EPI == 1) v += bias[col];
                if constexpr (EPI == 2) v *= invm[b * M + row] * invn[b * N + col] * scale;
                const long long idx = (long long)row * ldc + col;
                if constexpr (OMODE == OUT_F32) {
                    ((float*)Cb0)[idx] = v;
                } else if constexpr (OMODE == OUT_B16) {
                    ((us*)Cb0)[idx] = f2bf(v);
                } else {
                    us h, l; split_bf(v, h, l);
                    ((us*)Cb0)[idx] = h;
                    ((us*)Cb1)[idx] = l;
                }
            }
}

// =====================  small kernels  =====================

__global__ __launch_bounds__(256) void convert_w_k(
    const float* Wv, const float* Wt, us* Wvh, us* Wvl, us* Wth, us* Wtl)
{
    const int i = blockIdx.x * 256 + threadIdx.x;
    split_bf(Wv[i], Wvh[i], Wvl[i]);
    split_bf(Wt[i], Wth[i], Wtl[i]);
}

// mean over hw of img[b,c,:]; one wave per (b,c) row; grid 1024
__global__ __launch_bounds__(256) void mean_img_k(
    const float* __restrict__ img, float* __restrict__ mimg)
{
    const int row = blockIdx.x * 4 + (threadIdx.x >> 6);
    const int lane = threadIdx.x & 63;
    const float* p = img + (long long)row * 1024;
    float s = 0.f;
    #pragma unroll
    for (int c = 0; c < 4; ++c) {
        float4 v = *(const float4*)&p[(c * 64 + lane) * 4];
        s += v.x + v.y + v.z + v.w;
    }
    #pragma unroll
    for (int o = 32; o > 0; o >>= 1) s += __shfl_xor(s, o);
    if (lane == 0) mimg[row] = s * (1.0f / 1024.0f);
}

__global__ __launch_bounds__(256) void mean_text_s1(
    const float* __restrict__ text, float* __restrict__ part)
{
    const int b = blockIdx.x, ch = blockIdx.y, k = threadIdx.x;
    const float* p = text + ((long long)b * 512 + ch * 64) * 256 + k;
    float s = 0.f;
    for (int r = 0; r < 64; ++r) s += p[r * 256];
    part[(b * 8 + ch) * 256 + k] = s;
}
__global__ __launch_bounds__(256) void mean_text_s2(
    const float* __restrict__ part, float* __restrict__ mt)
{
    const int b = blockIdx.x, k = threadIdx.x;
    float s = 0.f;
    for (int c = 0; c < 8; ++c) s += part[(b * 8 + c) * 256 + k];
    mt[b * 256 + k] = s * (1.0f / 512.0f);
}

__global__ __launch_bounds__(256) void small_adapter_k(
    const float* __restrict__ x, const float* __restrict__ W,
    const float* __restrict__ bias, float* __restrict__ y)
{
    const int b = blockIdx.x, d = threadIdx.x;
    __shared__ float xs[256];
    xs[d] = x[b * 256 + d];
    __syncthreads();
    const float* w = W + (long long)d * 256;
    float s = bias[d];
    for (int k = 0; k < 256; ++k) s += xs[k] * w[k];
    y[b * 256 + d] = s;
}

// ---- parallelized global loss (R3: was a single 148us block) ----

// inv L2 norm of fp32 rows of width 256; one wave per row; grid rows/4
__global__ __launch_bounds__(256) void inv_norm_f32_k(
    const float* __restrict__ x, float* __restrict__ inv)
{
    const int row = blockIdx.x * 4 + (threadIdx.x >> 6);
    const int lane = threadIdx.x & 63;
    float4 v = *(const float4*)&x[(long long)row * 256 + lane * 4];
    float s = v.x * v.x + v.y * v.y + v.z * v.z + v.w * v.w;
    #pragma unroll
    for (int o = 32; o > 0; o >>= 1) s += __shfl_xor(s, o);
    if (lane == 0) inv[row] = 1.0f / fmaxf(sqrtf(s), 1e-8f);
}

// g_sim[i,j] = (gi[i].gt[j]) * invI[i]*invT[j] / tau;  grid 64 (one row each)
__global__ __launch_bounds__(256) void g_sim_k(
    const float* __restrict__ gi, const float* __restrict__ gt,
    const float* __restrict__ invI, const float* __restrict__ invT,
    float* __restrict__ gs)
{
    const int i = blockIdx.x, t = threadIdx.x;
    const int j = t >> 2, part = t & 3;
    __shared__ float a[256];
    a[t] = gi[i * 256 + t];
    __syncthreads();
    const float* bp = gt + (long long)j * 256 + part * 64;
    const float* ap = a + part * 64;
    float s = 0.f;
    #pragma unroll 16
    for (int k = 0; k < 64; ++k) s += ap[k] * bp[k];
    s += __shfl_xor(s, 1);
    s += __shfl_xor(s, 2);
    if (part == 0) gs[i * 64 + j] = s * invI[i] * invT[j] * TAU_INV;
}

// 64x64 symmetric CE: grid 128 one-wave blocks (64 rows then 64 cols)
__global__ __launch_bounds__(64) void g_lse_k(
    const float* __restrict__ gs, float* __restrict__ out)
{
    const int b = blockIdx.x, lane = threadIdx.x;
    const bool is_col = b >= 64;
    const int r = is_col ? b - 64 : b;
    const float v = is_col ? gs[lane * 64 + r] : gs[r * 64 + lane];
    float m = v;
    #pragma unroll
    for (int o = 32; o > 0; o >>= 1) m = fmaxf(m, __shfl_xor(m, o));
    float s = expf(v - m);
    #pragma unroll
    for (int o = 32; o > 0; o >>= 1) s += __shfl_xor(s, o);
    if (lane == 0)
        atomicAdd(out, ((m + logf(s)) - gs[r * 64 + r]) * (0.5f / 64.0f));
}

// minmax over p of bf16 sim, stage1: grid (128, 8); stage2: grid 128
__global__ __launch_bounds__(256) void minmax_s1(
    const us* __restrict__ simW, float* __restrict__ mnp, float* __restrict__ mxp)
{
    const int bx = blockIdx.x;
    const int b = bx >> 1, s = ((bx & 1) << 8) + threadIdx.x;
    const int ch = blockIdx.y;
    const us* p = simW + ((long long)b * 1024 + ch * 128) * 512 + s;
    float lo = 1e30f, hi = -1e30f;
    for (int r = 0; r < 128; ++r) {
        const float v = bf2f(p[(long long)r * 512]);
        lo = fminf(lo, v); hi = fmaxf(hi, v);
    }
    mnp[((long long)b * 8 + ch) * 512 + s] = lo;
    mxp[((long long)b * 8 + ch) * 512 + s] = hi;
}
__global__ __launch_bounds__(256) void minmax_s2(
    const float* __restrict__ mnp, const float* __restrict__ mxp,
    float* __restrict__ mn, float* __restrict__ mx)
{
    const int bx = blockIdx.x;
    const int b = bx >> 1, s = ((bx & 1) << 8) + threadIdx.x;
    float lo = 1e30f, hi = -1e30f;
    for (int c = 0; c < 8; ++c) {
        lo = fminf(lo, mnp[((long long)b * 8 + c) * 512 + s]);
        hi = fmaxf(hi, mxp[((long long)b * 8 + c) * 512 + s]);
    }
    mn[b * 512 + s] = lo;
    mx[b * 512 + s] = hi;
}

__global__ __launch_bounds__(256) void weights_bf_k(
    us* __restrict__ simW, const float* __restrict__ mn, const float* __restrict__ mx)
{
    const long long n8 = (long long)BB * HWP * SS / 8;
    for (long long i8 = (long long)blockIdx.x * 256 + threadIdx.x; i8 < n8;
         i8 += (long long)gridDim.x * 256) {
        const long long i = i8 * 8;
        const int b = (int)(i >> 19), s0 = (int)(i & 511);
        ushort8v v = *(const ushort8v*)&simW[i];
        const float* mnb = mn + b * 512;
        const float* mxb = mx + b * 512;
        ushort8v o;
        #pragma unroll
        for (int j = 0; j < 8; ++j) {
            const float lo = mnb[s0 + j], hi = mxb[s0 + j];
            const float w = (bf2f(v[j]) - lo) / (hi - lo + 1e-8f);
            o[j] = (w < SIGMA) ? (us)0 : f2bf(w);
        }
        *(ushort8v*)&simW[i] = o;
    }
}

__global__ __launch_bounds__(256) void inv_norm_spl_k(
    const us* __restrict__ xh, const us* __restrict__ xl, float* __restrict__ inv)
{
    const int row = blockIdx.x * 4 + (threadIdx.x >> 6);
    const int lane = threadIdx.x & 63;
    ushort4 h = *(const ushort4*)&xh[(long long)row * 256 + lane * 4];
    ushort4 l = *(const ushort4*)&xl[(long long)row * 256 + lane * 4];
    const float x0 = bf2f(h.x) + bf2f(l.x), x1 = bf2f(h.y) + bf2f(l.y);
    const float x2 = bf2f(h.z) + bf2f(l.z), x3 = bf2f(h.w) + bf2f(l.w);
    float s = x0 * x0 + x1 * x1 + x2 * x2 + x3 * x3;
    #pragma unroll
    for (int o = 32; o > 0; o >>= 1) s += __shfl_xor(s, o);
    if (lane == 0) inv[row] = 1.0f / fmaxf(sqrtf(s), 1e-8f);
}

__global__ __launch_bounds__(256) void row_lse_k(
    const float* __restrict__ f, float* __restrict__ out)
{
    const int r = blockIdx.x * 4 + (threadIdx.x >> 6);
    const int lane = threadIdx.x & 63;
    const float* p = f + (long long)r * SS;
    float vals[8];
    float4 v0 = *(const float4*)&p[lane * 8];
    float4 v1 = *(const float4*)&p[lane * 8 + 4];
    vals[0] = v0.x; vals[1] = v0.y; vals[2] = v0.z; vals[3] = v0.w;
    vals[4] = v1.x; vals[5] = v1.y; vals[6] = v1.z; vals[7] = v1.w;
    float m = -1e30f;
    #pragma unroll
    for (int t = 0; t < 8; ++t) m = fmaxf(m, vals[t]);
    #pragma unroll
    for (int o = 32; o > 0; o >>= 1) m = fmaxf(m, __shfl_xor(m, o));
    float s = 0.f;
    #pragma unroll
    for (int t = 0; t < 8; ++t) s += expf(vals[t] - m);
    #pragma unroll
    for (int o = 32; o > 0; o >>= 1) s += __shfl_xor(s, o);
    const float contrib = (m + logf(s)) - p[r & (SS - 1)];
    __shared__ float red[4];
    if (lane == 0) red[threadIdx.x >> 6] = contrib;
    __syncthreads();
    if (threadIdx.x == 0)
        atomicAdd(out, (red[0] + red[1] + red[2] + red[3]) * (0.5f / (64.0f * 512.0f)));
}

__global__ __launch_bounds__(256) void col_lse_k(
    const float* __restrict__ f, float* __restrict__ out)
{
    const int b = blockIdx.x >> 1;
    const int j = ((blockIdx.x & 1) << 8) + threadIdx.x;
    const float* p = f + (long long)b * SS * SS + j;
    float m = -1e30f, s = 0.f;
    for (int i = 0; i < SS; ++i) {
        const float x = p[(long long)i * SS];
        const float nm = fmaxf(m, x);
        s = s * expf(m - nm) + expf(x - nm);
        m = nm;
    }
    const float contrib = (m + logf(s)) - p[(long long)j * SS];
    __shared__ float red[256];
    red[threadIdx.x] = contrib;
    __syncthreads();
    for (int w = 128; w > 0; w >>= 1) {
        if (threadIdx.x < w) red[threadIdx.x] += red[threadIdx.x + w];
        __syncthreads();
    }
    if (threadIdx.x == 0) atomicAdd(out, red[0] * (0.5f / (64.0f * 512.0f)));
}

extern "C" void kernel_launch(void* const* d_in, const int* in_sizes, int n_in,
                              void* d_out, int out_size, void* d_ws, size_t ws_size,
                              hipStream_t stream)
{
    const float* img  = (const float*)d_in[0];
    const float* text = (const float*)d_in[1];
    const float* Wv   = (const float*)d_in[2];
    const float* bv   = (const float*)d_in[3];
    const float* Wt   = (const float*)d_in[4];
    const float* bt   = (const float*)d_in[5];
    float* out = (float*)d_out;
    char* ws = (char*)d_ws;

    us* patches_h = (us*)(ws + 0);
    us* patches_l = (us*)(ws + 33554432);
    us* tokens_h  = (us*)(ws + 67108864);
    us* tokens_l  = (us*)(ws + 83886080);
    us* simW      = (us*)(ws + 100663296);
    float* f_sim  = (float*)(ws + 100663296);
    us* lgve_h    = (us*)(ws + 167772160);
    us* lgve_l    = (us*)(ws + 184549376);
    char* st = ws + 201326592;
    float* mean_img  = (float*)(st + 0);
    float* mean_text = (float*)(st + 65536);
    float* mean_pat  = (float*)(st + 131072);
    float* mean_tok  = (float*)(st + 196608);
    float* g_img     = (float*)(st + 262144);
    float* g_txt     = (float*)(st + 327680);
    float* textpart  = (float*)(st + 393216);
    float* mnp       = (float*)(st + 917504);
    float* mxp       = (float*)(st + 1966080);
    float* mnv       = (float*)(st + 3014656);
    float* mxv       = (float*)(st + 3145728);
    float* inv_l     = (float*)(st + 3276800);
    float* inv_t     = (float*)(st + 3407872);
    us* Wvh = (us*)(st + 3538944);
    us* Wvl = (us*)(st + 3670016);
    us* Wth = (us*)(st + 3801088);
    us* Wtl = (us*)(st + 3932160);
    float* inv_gi  = (float*)(st + 4063232);
    float* inv_gt  = (float*)(st + 4063744);
    float* g_simbf = (float*)(st + 4064256);   // 64x64 f32

    zero_out_k<<<1, 64, 0, stream>>>(out);
    convert_w_k<<<256, 256, 0, stream>>>(Wv, Wt, Wvh, Wvl, Wth, Wtl);

    // Global path (mean commutes with linear)
    mean_img_k<<<4096, 256, 0, stream>>>(img, mean_img);
    mean_text_s1<<<dim3(64, 8), 256, 0, stream>>>(text, textpart);
    mean_text_s2<<<64, 256, 0, stream>>>(textpart, mean_text);
    small_adapter_k<<<BB, 256, 0, stream>>>(mean_img, Wv, bv, mean_pat);
    small_adapter_k<<<BB, 256, 0, stream>>>(mean_pat, Wv, bv, g_img);
    small_adapter_k<<<BB, 256, 0, stream>>>(mean_text, Wt, bt, mean_tok);
    small_adapter_k<<<BB, 256, 0, stream>>>(mean_tok, Wt, bt, g_txt);
    inv_norm_f32_k<<<16, 256, 0, stream>>>(g_img, inv_gi);
    inv_norm_f32_k<<<16, 256, 0, stream>>>(g_txt, inv_gt);
    g_sim_k<<<64, 256, 0, stream>>>(g_img, g_txt, inv_gi, inv_gt, g_simbf);
    g_lse_k<<<128, 64, 0, stream>>>(g_simbf, out);

    // G1: patches
    mfma_gemm<OPM_F32_COL, OPM_SPL_ROW, OUT_SPL, 1><<<dim3(8, 2, BB), 256, 0, stream>>>(
        img, nullptr, Wvh, Wvl, patches_h, patches_l,
        1024, 256, 256, 1024, 256, 256,
        1048576LL, 0LL, 524288LL, bv, nullptr, nullptr, 0.f);

    // G2: tokens
    mfma_gemm<OPM_F32_ROW, OPM_SPL_ROW, OUT_SPL, 1><<<dim3(4, 2, BB), 256, 0, stream>>>(
        text, nullptr, Wth, Wtl, tokens_h, tokens_l,
        512, 256, 256, 256, 256, 256,
        524288LL, 0LL, 262144LL, bt, nullptr, nullptr, 0.f);

    // G4: sim -> bf16
    mfma_gemm<OPM_SPL_ROW, OPM_SPL_ROW, OUT_B16, 0><<<dim3(8, 4, BB), 256, 0, stream>>>(
        patches_h, patches_l, tokens_h, tokens_l, simW, nullptr,
        1024, 512, 256, 256, 256, 512,
        524288LL, 262144LL, 1048576LL, nullptr, nullptr, nullptr, 0.f);

    // min-max + threshold weights (in-place bf16)
    minmax_s1<<<dim3(128, 8), 256, 0, stream>>>(simW, mnp, mxp);
    minmax_s2<<<128, 256, 0, stream>>>(mnp, mxp, mnv, mxv);
    weights_bf_k<<<4096, 256, 0, stream>>>(simW, mnv, mxv);

    // G6: lgve (L1 norm dropped: positive row scale cancels in later L2 norm)
    mfma_gemm<OPM_B16_COL, OPM_SPL_COL, OUT_SPL, 0><<<dim3(4, 2, BB), 256, 0, stream>>>(
        simW, nullptr, patches_h, patches_l, lgve_h, lgve_l,
        512, 256, 1024, 512, 256, 256,
        1048576LL, 524288LL, 262144LL, nullptr, nullptr, nullptr, 0.f);

    // inverse L2 norms
    inv_norm_spl_k<<<8192, 256, 0, stream>>>(lgve_h, lgve_l, inv_l);
    inv_norm_spl_k<<<8192, 256, 0, stream>>>(tokens_h, tokens_l, inv_t);

    // G8: f_sim -> fp32 with cos epilogue
    mfma_gemm<OPM_SPL_ROW, OPM_SPL_ROW, OUT_F32, 2><<<dim3(4, 4, BB), 256, 0, stream>>>(
        lgve_h, lgve_l, tokens_h, tokens_l, f_sim, nullptr,
        512, 512, 256, 256, 256, 512,
        262144LL, 262144LL, 1048576LL, nullptr, inv_l, inv_t, TAU_INV);

    // fine-grained symmetric CE
    row_lse_k<<<8192, 256, 0, stream>>>(f_sim, out);
    col_lse_k<<<128, 256, 0, stream>>>(f_sim, out);
}

// Round 5
// 661.289 us; speedup vs baseline: 2.4290x; 1.1107x over previous
//
#include <hip/hip_runtime.h>
#include <math.h>

#define BB   64
#define HWP  1024
#define SS   512
#define DD   256
#define TAU_INV (1.0f/0.07f)
#define SIGMA   (1.0f/1024.0f)

typedef unsigned short us;
typedef __attribute__((ext_vector_type(8))) short short8v;
typedef __attribute__((ext_vector_type(8))) unsigned short ushort8v;
typedef __attribute__((ext_vector_type(4))) float floatx4;

__device__ __forceinline__ float bf2f(us u) {
    return __uint_as_float((unsigned)u << 16);
}
__device__ __forceinline__ us f2bf(float f) {
    unsigned u = __float_as_uint(f);
    u += 0x7FFFu + ((u >> 16) & 1u);
    return (us)(u >> 16);
}
__device__ __forceinline__ void split_bf(float v, us& h, us& l) {
    h = f2bf(v);
    l = f2bf(v - bf2f(h));
}

__global__ void zero_out_k(float* out) { if (threadIdx.x == 0) out[0] = 0.0f; }

// =====================  MFMA GEMM  =====================
// C[m,n] = sum_k A(m,k)*B(n,k), 128x128 tile, BK=32, 16x16x32 bf16 MFMA,
// split-bf16 operands (hi+lo): AB ~= AhBh + AhBl + AlBh.
enum { OPM_F32_ROW = 0, OPM_F32_COL = 1, OPM_SPL_ROW = 2, OPM_SPL_COL = 3,
       OPM_B16_COL = 4 };
enum { OUT_F32 = 0, OUT_B16 = 1, OUT_SPL = 2 };

#define LDSTRIDE 40

// COL staging (R4 rewrite): thread-per-m, loop-over-k register gather.
// Global loads are coalesced (lanes = consecutive m = contiguous dim of a
// K-major source); LDS stores are b128 along the row -> 64 lanes hit 8
// disjoint 4-bank windows covering all 32 banks -> conflict-free.
// (Old scalar transposed stores were a structural 8-way conflict: 60% of G6.)
template<int MODE>
__device__ __forceinline__ void stage_tile(
    const char* p0, const char* p1, int ld, int row0, int k0,
    us* ldsH, us* ldsL, int tid)
{
    if constexpr (MODE == OPM_SPL_ROW) {
        const us* ph = (const us*)p0;
        const us* pl = (const us*)p1;
        const int i = tid >> 1, ko = (tid & 1) * 16;
        const long long g = (long long)(row0 + i) * ld + k0 + ko;
        *(ushort8v*)&ldsH[i * LDSTRIDE + ko]     = *(const ushort8v*)&ph[g];
        *(ushort8v*)&ldsH[i * LDSTRIDE + ko + 8] = *(const ushort8v*)&ph[g + 8];
        *(ushort8v*)&ldsL[i * LDSTRIDE + ko]     = *(const ushort8v*)&pl[g];
        *(ushort8v*)&ldsL[i * LDSTRIDE + ko + 8] = *(const ushort8v*)&pl[g + 8];
    } else if constexpr (MODE == OPM_F32_ROW) {
        const float* pf = (const float*)p0;
        const int i = tid >> 1, ko = (tid & 1) * 16;
        const long long g = (long long)(row0 + i) * ld + k0 + ko;
        us h16[16], l16[16];
        #pragma unroll
        for (int c = 0; c < 16; c += 4) {
            float4 v = *(const float4*)&pf[g + c];
            split_bf(v.x, h16[c+0], l16[c+0]); split_bf(v.y, h16[c+1], l16[c+1]);
            split_bf(v.z, h16[c+2], l16[c+2]); split_bf(v.w, h16[c+3], l16[c+3]);
        }
        *(ushort8v*)&ldsH[i * LDSTRIDE + ko]     = *(const ushort8v*)&h16[0];
        *(ushort8v*)&ldsH[i * LDSTRIDE + ko + 8] = *(const ushort8v*)&h16[8];
        *(ushort8v*)&ldsL[i * LDSTRIDE + ko]     = *(const ushort8v*)&l16[0];
        *(ushort8v*)&ldsL[i * LDSTRIDE + ko + 8] = *(const ushort8v*)&l16[8];
    } else if constexpr (MODE == OPM_F32_COL) {
        const float* pf = (const float*)p0;
        const int m = tid & 127, kh = (tid >> 7) * 16;
        const long long base = (long long)(k0 + kh) * ld + row0 + m;
        us vh[16], vl[16];
        #pragma unroll
        for (int kk = 0; kk < 16; ++kk)
            split_bf(pf[base + (long long)kk * ld], vh[kk], vl[kk]);
        *(ushort8v*)&ldsH[m * LDSTRIDE + kh]     = *(const ushort8v*)&vh[0];
        *(ushort8v*)&ldsH[m * LDSTRIDE + kh + 8] = *(const ushort8v*)&vh[8];
        *(ushort8v*)&ldsL[m * LDSTRIDE + kh]     = *(const ushort8v*)&vl[0];
        *(ushort8v*)&ldsL[m * LDSTRIDE + kh + 8] = *(const ushort8v*)&vl[8];
    } else if constexpr (MODE == OPM_B16_COL) {
        const us* ph = (const us*)p0;
        const int m = tid & 127, kh = (tid >> 7) * 16;
        const long long base = (long long)(k0 + kh) * ld + row0 + m;
        us v[16];
        #pragma unroll
        for (int kk = 0; kk < 16; ++kk)
            v[kk] = ph[base + (long long)kk * ld];
        *(ushort8v*)&ldsH[m * LDSTRIDE + kh]     = *(const ushort8v*)&v[0];
        *(ushort8v*)&ldsH[m * LDSTRIDE + kh + 8] = *(const ushort8v*)&v[8];
    } else if constexpr (MODE == OPM_SPL_COL) {
        const us* ph = (const us*)p0;
        const us* pl = (const us*)p1;
        const int m = tid & 127, kh = (tid >> 7) * 16;
        const long long base = (long long)(k0 + kh) * ld + row0 + m;
        us vh[16], vl[16];
        #pragma unroll
        for (int kk = 0; kk < 16; ++kk) {
            vh[kk] = ph[base + (long long)kk * ld];
            vl[kk] = pl[base + (long long)kk * ld];
        }
        *(ushort8v*)&ldsH[m * LDSTRIDE + kh]     = *(const ushort8v*)&vh[0];
        *(ushort8v*)&ldsH[m * LDSTRIDE + kh + 8] = *(const ushort8v*)&vh[8];
        *(ushort8v*)&ldsL[m * LDSTRIDE + kh]     = *(const ushort8v*)&vl[0];
        *(ushort8v*)&ldsL[m * LDSTRIDE + kh + 8] = *(const ushort8v*)&vl[8];
    }
}

template<int AMODE, int BMODE, int OMODE, int EPI>
__global__ __launch_bounds__(256) void mfma_gemm(
    const void* A0, const void* A1, const void* B0, const void* B1,
    void* C0, void* C1,
    int M, int N, int K, int lda, int ldb, int ldc,
    long long sA, long long sB, long long sC,
    const float* __restrict__ bias, const float* __restrict__ invm,
    const float* __restrict__ invn, float scale)
{
    constexpr bool ASPL = (AMODE != OPM_B16_COL);
    constexpr bool BSPL = (BMODE != OPM_B16_COL);
    constexpr int ASZ = 128 * LDSTRIDE;
    __shared__ __align__(16) us Ah[ASZ];
    __shared__ __align__(16) us Al[ASPL ? ASZ : 8];
    __shared__ __align__(16) us Bh[ASZ];
    __shared__ __align__(16) us Bl[BSPL ? ASZ : 8];

    const int tid = threadIdx.x;
    const int w = tid >> 6, lane = tid & 63;
    const int quad = lane >> 4, l16 = lane & 15;
    const int m0 = blockIdx.x * 128, n0 = blockIdx.y * 128;
    const int b = blockIdx.z;

    const char* Ab0 = (const char*)A0 + (long long)b * sA;
    const char* Ab1 = A1 ? (const char*)A1 + (long long)b * sA : nullptr;
    const char* Bb0 = (const char*)B0 + (long long)b * sB;
    const char* Bb1 = B1 ? (const char*)B1 + (long long)b * sB : nullptr;

    floatx4 acc[2][8];
    #pragma unroll
    for (int mi = 0; mi < 2; ++mi)
        #pragma unroll
        for (int ni = 0; ni < 8; ++ni)
            acc[mi][ni] = (floatx4){0.f, 0.f, 0.f, 0.f};

    for (int k0 = 0; k0 < K; k0 += 32) {
        stage_tile<AMODE>(Ab0, Ab1, lda, m0, k0, Ah, Al, tid);
        stage_tile<BMODE>(Bb0, Bb1, ldb, n0, k0, Bh, Bl, tid);
        __syncthreads();

        short8v ah[2], al[2], bh[8], bl[8];
        #pragma unroll
        for (int mi = 0; mi < 2; ++mi) {
            const int r = (32 * w + 16 * mi + l16) * LDSTRIDE + quad * 8;
            ah[mi] = *(const short8v*)&Ah[r];
            if constexpr (ASPL) al[mi] = *(const short8v*)&Al[r];
        }
        #pragma unroll
        for (int ni = 0; ni < 8; ++ni) {
            const int r = (16 * ni + l16) * LDSTRIDE + quad * 8;
            bh[ni] = *(const short8v*)&Bh[r];
            if constexpr (BSPL) bl[ni] = *(const short8v*)&Bl[r];
        }
        #pragma unroll
        for (int mi = 0; mi < 2; ++mi)
            #pragma unroll
            for (int ni = 0; ni < 8; ++ni) {
                acc[mi][ni] = __builtin_amdgcn_mfma_f32_16x16x32_bf16(ah[mi], bh[ni], acc[mi][ni], 0, 0, 0);
                if constexpr (BSPL)
                    acc[mi][ni] = __builtin_amdgcn_mfma_f32_16x16x32_bf16(ah[mi], bl[ni], acc[mi][ni], 0, 0, 0);
                if constexpr (ASPL)
                    acc[mi][ni] = __builtin_amdgcn_mfma_f32_16x16x32_bf16(al[mi], bh[ni], acc[mi][ni], 0, 0, 0);
            }
        __syncthreads();
    }

    char* Cb0 = (char*)C0 + (long long)b * sC;
    char* Cb1 = C1 ? (char*)C1 + (long long)b * sC : nullptr;
    #pragma unroll
    for (int mi = 0; mi < 2; ++mi)
        #pragma unroll
        for (int ni = 0; ni < 8; ++ni)
            #pragma unroll
            for (int r = 0; r < 4; ++r) {
                const int row = m0 + 32 * w + 16 * mi + quad * 4 + r;
                const int col = n0 + 16 * ni + l16;
                float v = acc[mi][ni][r];
                if constexpr (EPI == 1) v += bias[col];
                if constexpr (EPI == 2) v *= invm[b * M + row] * invn[b * N + col] * scale;
                const long long idx = (long long)row * ldc + col;
                if constexpr (OMODE == OUT_F32) {
                    ((float*)Cb0)[idx] = v;
                } else if constexpr (OMODE == OUT_B16) {
                    ((us*)Cb0)[idx] = f2bf(v);
                } else {
                    us h, l; split_bf(v, h, l);
                    ((us*)Cb0)[idx] = h;
                    ((us*)Cb1)[idx] = l;
                }
            }
}

// =====================  small kernels  =====================

__global__ __launch_bounds__(256) void convert_w_k(
    const float* Wv, const float* Wt, us* Wvh, us* Wvl, us* Wth, us* Wtl)
{
    const int i = blockIdx.x * 256 + threadIdx.x;
    split_bf(Wv[i], Wvh[i], Wvl[i]);
    split_bf(Wt[i], Wth[i], Wtl[i]);
}

__global__ __launch_bounds__(256) void mean_img_k(
    const float* __restrict__ img, float* __restrict__ mimg)
{
    const int row = blockIdx.x * 4 + (threadIdx.x >> 6);
    const int lane = threadIdx.x & 63;
    const float* p = img + (long long)row * 1024;
    float s = 0.f;
    #pragma unroll
    for (int c = 0; c < 4; ++c) {
        float4 v = *(const float4*)&p[(c * 64 + lane) * 4];
        s += v.x + v.y + v.z + v.w;
    }
    #pragma unroll
    for (int o = 32; o > 0; o >>= 1) s += __shfl_xor(s, o);
    if (lane == 0) mimg[row] = s * (1.0f / 1024.0f);
}

__global__ __launch_bounds__(256) void mean_text_s1(
    const float* __restrict__ text, float* __restrict__ part)
{
    const int b = blockIdx.x, ch = blockIdx.y, k = threadIdx.x;
    const float* p = text + ((long long)b * 512 + ch * 64) * 256 + k;
    float s = 0.f;
    for (int r = 0; r < 64; ++r) s += p[r * 256];
    part[(b * 8 + ch) * 256 + k] = s;
}
__global__ __launch_bounds__(256) void mean_text_s2(
    const float* __restrict__ part, float* __restrict__ mt)
{
    const int b = blockIdx.x, k = threadIdx.x;
    float s = 0.f;
    for (int c = 0; c < 8; ++c) s += part[(b * 8 + c) * 256 + k];
    mt[b * 256 + k] = s * (1.0f / 512.0f);
}

__global__ __launch_bounds__(256) void small_adapter_k(
    const float* __restrict__ x, const float* __restrict__ W,
    const float* __restrict__ bias, float* __restrict__ y)
{
    const int b = blockIdx.x, d = threadIdx.x;
    __shared__ float xs[256];
    xs[d] = x[b * 256 + d];
    __syncthreads();
    const float* w = W + (long long)d * 256;
    float s = bias[d];
    for (int k = 0; k < 256; ++k) s += xs[k] * w[k];
    y[b * 256 + d] = s;
}

// ---- parallelized global loss ----

__global__ __launch_bounds__(256) void inv_norm_f32_k(
    const float* __restrict__ x, float* __restrict__ inv)
{
    const int row = blockIdx.x * 4 + (threadIdx.x >> 6);
    const int lane = threadIdx.x & 63;
    float4 v = *(const float4*)&x[(long long)row * 256 + lane * 4];
    float s = v.x * v.x + v.y * v.y + v.z * v.z + v.w * v.w;
    #pragma unroll
    for (int o = 32; o > 0; o >>= 1) s += __shfl_xor(s, o);
    if (lane == 0) inv[row] = 1.0f / fmaxf(sqrtf(s), 1e-8f);
}

__global__ __launch_bounds__(256) void g_sim_k(
    const float* __restrict__ gi, const float* __restrict__ gt,
    const float* __restrict__ invI, const float* __restrict__ invT,
    float* __restrict__ gs)
{
    const int i = blockIdx.x, t = threadIdx.x;
    const int j = t >> 2, part = t & 3;
    __shared__ float a[256];
    a[t] = gi[i * 256 + t];
    __syncthreads();
    const float* bp = gt + (long long)j * 256 + part * 64;
    const float* ap = a + part * 64;
    float s = 0.f;
    #pragma unroll 16
    for (int k = 0; k < 64; ++k) s += ap[k] * bp[k];
    s += __shfl_xor(s, 1);
    s += __shfl_xor(s, 2);
    if (part == 0) gs[i * 64 + j] = s * invI[i] * invT[j] * TAU_INV;
}

__global__ __launch_bounds__(64) void g_lse_k(
    const float* __restrict__ gs, float* __restrict__ out)
{
    const int b = blockIdx.x, lane = threadIdx.x;
    const bool is_col = b >= 64;
    const int r = is_col ? b - 64 : b;
    const float v = is_col ? gs[lane * 64 + r] : gs[r * 64 + lane];
    float m = v;
    #pragma unroll
    for (int o = 32; o > 0; o >>= 1) m = fmaxf(m, __shfl_xor(m, o));
    float s = expf(v - m);
    #pragma unroll
    for (int o = 32; o > 0; o >>= 1) s += __shfl_xor(s, o);
    if (lane == 0)
        atomicAdd(out, ((m + logf(s)) - gs[r * 64 + r]) * (0.5f / 64.0f));
}

// minmax over p of bf16 sim, stage1: grid (128, 8); stage2: grid 128
__global__ __launch_bounds__(256) void minmax_s1(
    const us* __restrict__ simW, float* __restrict__ mnp, float* __restrict__ mxp)
{
    const int bx = blockIdx.x;
    const int b = bx >> 1, s = ((bx & 1) << 8) + threadIdx.x;
    const int ch = blockIdx.y;
    const us* p = simW + ((long long)b * 1024 + ch * 128) * 512 + s;
    float lo = 1e30f, hi = -1e30f;
    for (int r = 0; r < 128; ++r) {
        const float v = bf2f(p[(long long)r * 512]);
        lo = fminf(lo, v); hi = fmaxf(hi, v);
    }
    mnp[((long long)b * 8 + ch) * 512 + s] = lo;
    mxp[((long long)b * 8 + ch) * 512 + s] = hi;
}
__global__ __launch_bounds__(256) void minmax_s2(
    const float* __restrict__ mnp, const float* __restrict__ mxp,
    float* __restrict__ mn, float* __restrict__ mx)
{
    const int bx = blockIdx.x;
    const int b = bx >> 1, s = ((bx & 1) << 8) + threadIdx.x;
    float lo = 1e30f, hi = -1e30f;
    for (int c = 0; c < 8; ++c) {
        lo = fminf(lo, mnp[((long long)b * 8 + c) * 512 + s]);
        hi = fmaxf(hi, mxp[((long long)b * 8 + c) * 512 + s]);
    }
    mn[b * 512 + s] = lo;
    mx[b * 512 + s] = hi;
}

__global__ __launch_bounds__(256) void weights_bf_k(
    us* __restrict__ simW, const float* __restrict__ mn, const float* __restrict__ mx)
{
    const long long n8 = (long long)BB * HWP * SS / 8;
    for (long long i8 = (long long)blockIdx.x * 256 + threadIdx.x; i8 < n8;
         i8 += (long long)gridDim.x * 256) {
        const long long i = i8 * 8;
        const int b = (int)(i >> 19), s0 = (int)(i & 511);
        ushort8v v = *(const ushort8v*)&simW[i];
        const float* mnb = mn + b * 512;
        const float* mxb = mx + b * 512;
        ushort8v o;
        #pragma unroll
        for (int j = 0; j < 8; ++j) {
            const float lo = mnb[s0 + j], hi = mxb[s0 + j];
            const float w = (bf2f(v[j]) - lo) / (hi - lo + 1e-8f);
            o[j] = (w < SIGMA) ? (us)0 : f2bf(w);
        }
        *(ushort8v*)&simW[i] = o;
    }
}

__global__ __launch_bounds__(256) void inv_norm_spl_k(
    const us* __restrict__ xh, const us* __restrict__ xl, float* __restrict__ inv)
{
    const int row = blockIdx.x * 4 + (threadIdx.x >> 6);
    const int lane = threadIdx.x & 63;
    ushort4 h = *(const ushort4*)&xh[(long long)row * 256 + lane * 4];
    ushort4 l = *(const ushort4*)&xl[(long long)row * 256 + lane * 4];
    const float x0 = bf2f(h.x) + bf2f(l.x), x1 = bf2f(h.y) + bf2f(l.y);
    const float x2 = bf2f(h.z) + bf2f(l.z), x3 = bf2f(h.w) + bf2f(l.w);
    float s = x0 * x0 + x1 * x1 + x2 * x2 + x3 * x3;
    #pragma unroll
    for (int o = 32; o > 0; o >>= 1) s += __shfl_xor(s, o);
    if (lane == 0) inv[row] = 1.0f / fmaxf(sqrtf(s), 1e-8f);
}

__global__ __launch_bounds__(256) void row_lse_k(
    const float* __restrict__ f, float* __restrict__ out)
{
    const int r = blockIdx.x * 4 + (threadIdx.x >> 6);
    const int lane = threadIdx.x & 63;
    const float* p = f + (long long)r * SS;
    float vals[8];
    float4 v0 = *(const float4*)&p[lane * 8];
    float4 v1 = *(const float4*)&p[lane * 8 + 4];
    vals[0] = v0.x; vals[1] = v0.y; vals[2] = v0.z; vals[3] = v0.w;
    vals[4] = v1.x; vals[5] = v1.y; vals[6] = v1.z; vals[7] = v1.w;
    float m = -1e30f;
    #pragma unroll
    for (int t = 0; t < 8; ++t) m = fmaxf(m, vals[t]);
    #pragma unroll
    for (int o = 32; o > 0; o >>= 1) m = fmaxf(m, __shfl_xor(m, o));
    float s = 0.f;
    #pragma unroll
    for (int t = 0; t < 8; ++t) s += expf(vals[t] - m);
    #pragma unroll
    for (int o = 32; o > 0; o >>= 1) s += __shfl_xor(s, o);
    const float contrib = (m + logf(s)) - p[r & (SS - 1)];
    __shared__ float red[4];
    if (lane == 0) red[threadIdx.x >> 6] = contrib;
    __syncthreads();
    if (threadIdx.x == 0)
        atomicAdd(out, (red[0] + red[1] + red[2] + red[3]) * (0.5f / (64.0f * 512.0f)));
}

__global__ __launch_bounds__(256) void col_lse_k(
    const float* __restrict__ f, float* __restrict__ out)
{
    const int b = blockIdx.x >> 1;
    const int j = ((blockIdx.x & 1) << 8) + threadIdx.x;
    const float* p = f + (long long)b * SS * SS + j;
    float m = -1e30f, s = 0.f;
    for (int i = 0; i < SS; ++i) {
        const float x = p[(long long)i * SS];
        const float nm = fmaxf(m, x);
        s = s * expf(m - nm) + expf(x - nm);
        m = nm;
    }
    const float contrib = (m + logf(s)) - p[(long long)j * SS];
    __shared__ float red[256];
    red[threadIdx.x] = contrib;
    __syncthreads();
    for (int w = 128; w > 0; w >>= 1) {
        if (threadIdx.x < w) red[threadIdx.x] += red[threadIdx.x + w];
        __syncthreads();
    }
    if (threadIdx.x == 0) atomicAdd(out, red[0] * (0.5f / (64.0f * 512.0f)));
}

extern "C" void kernel_launch(void* const* d_in, const int* in_sizes, int n_in,
                              void* d_out, int out_size, void* d_ws, size_t ws_size,
                              hipStream_t stream)
{
    const float* img  = (const float*)d_in[0];
    const float* text = (const float*)d_in[1];
    const float* Wv   = (const float*)d_in[2];
    const float* bv   = (const float*)d_in[3];
    const float* Wt   = (const float*)d_in[4];
    const float* bt   = (const float*)d_in[5];
    float* out = (float*)d_out;
    char* ws = (char*)d_ws;

    us* patches_h = (us*)(ws + 0);
    us* patches_l = (us*)(ws + 33554432);
    us* tokens_h  = (us*)(ws + 67108864);
    us* tokens_l  = (us*)(ws + 83886080);
    us* simW      = (us*)(ws + 100663296);
    float* f_sim  = (float*)(ws + 100663296);
    us* lgve_h    = (us*)(ws + 167772160);
    us* lgve_l    = (us*)(ws + 184549376);
    char* st = ws + 201326592;
    float* mean_img  = (float*)(st + 0);
    float* mean_text = (float*)(st + 65536);
    float* mean_pat  = (float*)(st + 131072);
    float* mean_tok  = (float*)(st + 196608);
    float* g_img     = (float*)(st + 262144);
    float* g_txt     = (float*)(st + 327680);
    float* textpart  = (float*)(st + 393216);
    float* mnp       = (float*)(st + 917504);
    float* mxp       = (float*)(st + 1966080);
    float* mnv       = (float*)(st + 3014656);
    float* mxv       = (float*)(st + 3145728);
    float* inv_l     = (float*)(st + 3276800);
    float* inv_t     = (float*)(st + 3407872);
    us* Wvh = (us*)(st + 3538944);
    us* Wvl = (us*)(st + 3670016);
    us* Wth = (us*)(st + 3801088);
    us* Wtl = (us*)(st + 3932160);
    float* inv_gi  = (float*)(st + 4063232);
    float* inv_gt  = (float*)(st + 4063744);
    float* g_simbf = (float*)(st + 4064256);

    zero_out_k<<<1, 64, 0, stream>>>(out);
    convert_w_k<<<256, 256, 0, stream>>>(Wv, Wt, Wvh, Wvl, Wth, Wtl);

    // Global path (mean commutes with linear)
    mean_img_k<<<4096, 256, 0, stream>>>(img, mean_img);
    mean_text_s1<<<dim3(64, 8), 256, 0, stream>>>(text, textpart);
    mean_text_s2<<<64, 256, 0, stream>>>(textpart, mean_text);
    small_adapter_k<<<BB, 256, 0, stream>>>(mean_img, Wv, bv, mean_pat);
    small_adapter_k<<<BB, 256, 0, stream>>>(mean_pat, Wv, bv, g_img);
    small_adapter_k<<<BB, 256, 0, stream>>>(mean_text, Wt, bt, mean_tok);
    small_adapter_k<<<BB, 256, 0, stream>>>(mean_tok, Wt, bt, g_txt);
    inv_norm_f32_k<<<16, 256, 0, stream>>>(g_img, inv_gi);
    inv_norm_f32_k<<<16, 256, 0, stream>>>(g_txt, inv_gt);
    g_sim_k<<<64, 256, 0, stream>>>(g_img, g_txt, inv_gi, inv_gt, g_simbf);
    g_lse_k<<<128, 64, 0, stream>>>(g_simbf, out);

    // G1: patches
    mfma_gemm<OPM_F32_COL, OPM_SPL_ROW, OUT_SPL, 1><<<dim3(8, 2, BB), 256, 0, stream>>>(
        img, nullptr, Wvh, Wvl, patches_h, patches_l,
        1024, 256, 256, 1024, 256, 256,
        1048576LL, 0LL, 524288LL, bv, nullptr, nullptr, 0.f);

    // G2: tokens
    mfma_gemm<OPM_F32_ROW, OPM_SPL_ROW, OUT_SPL, 1><<<dim3(4, 2, BB), 256, 0, stream>>>(
        text, nullptr, Wth, Wtl, tokens_h, tokens_l,
        512, 256, 256, 256, 256, 256,
        524288LL, 0LL, 262144LL, bt, nullptr, nullptr, 0.f);

    // G4: sim -> bf16
    mfma_gemm<OPM_SPL_ROW, OPM_SPL_ROW, OUT_B16, 0><<<dim3(8, 4, BB), 256, 0, stream>>>(
        patches_h, patches_l, tokens_h, tokens_l, simW, nullptr,
        1024, 512, 256, 256, 256, 512,
        524288LL, 262144LL, 1048576LL, nullptr, nullptr, nullptr, 0.f);

    // min-max + threshold weights (in-place bf16)
    minmax_s1<<<dim3(128, 8), 256, 0, stream>>>(simW, mnp, mxp);
    minmax_s2<<<128, 256, 0, stream>>>(mnp, mxp, mnv, mxv);
    weights_bf_k<<<4096, 256, 0, stream>>>(simW, mnv, mxv);

    // G6: lgve (L1 norm dropped: positive row scale cancels in later L2 norm)
    mfma_gemm<OPM_B16_COL, OPM_SPL_COL, OUT_SPL, 0><<<dim3(4, 2, BB), 256, 0, stream>>>(
        simW, nullptr, patches_h, patches_l, lgve_h, lgve_l,
        512, 256, 1024, 512, 256, 256,
        1048576LL, 524288LL, 262144LL, nullptr, nullptr, nullptr, 0.f);

    // inverse L2 norms
    inv_norm_spl_k<<<8192, 256, 0, stream>>>(lgve_h, lgve_l, inv_l);
    inv_norm_spl_k<<<8192, 256, 0, stream>>>(tokens_h, tokens_l, inv_t);

    // G8: f_sim -> fp32 with cos epilogue
    mfma_gemm<OPM_SPL_ROW, OPM_SPL_ROW, OUT_F32, 2><<<dim3(4, 4, BB), 256, 0, stream>>>(
        lgve_h, lgve_l, tokens_h, tokens_l, f_sim, nullptr,
        512, 512, 256, 256, 256, 512,
        262144LL, 262144LL, 1048576LL, nullptr, inv_l, inv_t, TAU_INV);

    // fine-grained symmetric CE
    row_lse_k<<<8192, 256, 0, stream>>>(f_sim, out);
    col_lse_k<<<128, 256, 0, stream>>>(f_sim, out);
}

// Round 6
// 636.740 us; speedup vs baseline: 2.5226x; 1.0386x over previous
//
#include <hip/hip_runtime.h>
#include <math.h>

#define BB   64
#define HWP  1024
#define SS   512
#define DD   256
#define TAU_INV (1.0f/0.07f)
#define SIGMA   (1.0f/1024.0f)

typedef unsigned short us;
typedef __attribute__((ext_vector_type(8))) short short8v;
typedef __attribute__((ext_vector_type(8))) unsigned short ushort8v;
typedef __attribute__((ext_vector_type(4))) float floatx4;

__device__ __forceinline__ float bf2f(us u) {
    return __uint_as_float((unsigned)u << 16);
}
__device__ __forceinline__ us f2bf(float f) {
    unsigned u = __float_as_uint(f);
    u += 0x7FFFu + ((u >> 16) & 1u);
    return (us)(u >> 16);
}
__device__ __forceinline__ void split_bf(float v, us& h, us& l) {
    h = f2bf(v);
    l = f2bf(v - bf2f(h));
}

__global__ void zero_out_k(float* out) { if (threadIdx.x == 0) out[0] = 0.0f; }

// =====================  MFMA GEMM  =====================
// C[m,n] = sum_k A(m,k)*B(n,k), 128x128 tile, BK=32, 16x16x32 bf16 MFMA,
// split-bf16 operands (hi+lo): AB ~= AhBh + AhBl + AlBh.
enum { OPM_F32_ROW = 0, OPM_F32_COL = 1, OPM_SPL_ROW = 2, OPM_SPL_COL = 3,
       OPM_B16_COL = 4 };
enum { OUT_F32 = 0, OUT_B16 = 1, OUT_SPL = 2 };

#define LDSTRIDE 40

// COL staging: thread-per-m register gather, b128 row stores (conflict-free).
template<int MODE>
__device__ __forceinline__ void stage_tile(
    const char* p0, const char* p1, int ld, int row0, int k0,
    us* ldsH, us* ldsL, int tid)
{
    if constexpr (MODE == OPM_SPL_ROW) {
        const us* ph = (const us*)p0;
        const us* pl = (const us*)p1;
        const int i = tid >> 1, ko = (tid & 1) * 16;
        const long long g = (long long)(row0 + i) * ld + k0 + ko;
        *(ushort8v*)&ldsH[i * LDSTRIDE + ko]     = *(const ushort8v*)&ph[g];
        *(ushort8v*)&ldsH[i * LDSTRIDE + ko + 8] = *(const ushort8v*)&ph[g + 8];
        *(ushort8v*)&ldsL[i * LDSTRIDE + ko]     = *(const ushort8v*)&pl[g];
        *(ushort8v*)&ldsL[i * LDSTRIDE + ko + 8] = *(const ushort8v*)&pl[g + 8];
    } else if constexpr (MODE == OPM_F32_ROW) {
        const float* pf = (const float*)p0;
        const int i = tid >> 1, ko = (tid & 1) * 16;
        const long long g = (long long)(row0 + i) * ld + k0 + ko;
        us h16[16], l16[16];
        #pragma unroll
        for (int c = 0; c < 16; c += 4) {
            float4 v = *(const float4*)&pf[g + c];
            split_bf(v.x, h16[c+0], l16[c+0]); split_bf(v.y, h16[c+1], l16[c+1]);
            split_bf(v.z, h16[c+2], l16[c+2]); split_bf(v.w, h16[c+3], l16[c+3]);
        }
        *(ushort8v*)&ldsH[i * LDSTRIDE + ko]     = *(const ushort8v*)&h16[0];
        *(ushort8v*)&ldsH[i * LDSTRIDE + ko + 8] = *(const ushort8v*)&h16[8];
        *(ushort8v*)&ldsL[i * LDSTRIDE + ko]     = *(const ushort8v*)&l16[0];
        *(ushort8v*)&ldsL[i * LDSTRIDE + ko + 8] = *(const ushort8v*)&l16[8];
    } else if constexpr (MODE == OPM_F32_COL) {
        const float* pf = (const float*)p0;
        const int m = tid & 127, kh = (tid >> 7) * 16;
        const long long base = (long long)(k0 + kh) * ld + row0 + m;
        us vh[16], vl[16];
        #pragma unroll
        for (int kk = 0; kk < 16; ++kk)
            split_bf(pf[base + (long long)kk * ld], vh[kk], vl[kk]);
        *(ushort8v*)&ldsH[m * LDSTRIDE + kh]     = *(const ushort8v*)&vh[0];
        *(ushort8v*)&ldsH[m * LDSTRIDE + kh + 8] = *(const ushort8v*)&vh[8];
        *(ushort8v*)&ldsL[m * LDSTRIDE + kh]     = *(const ushort8v*)&vl[0];
        *(ushort8v*)&ldsL[m * LDSTRIDE + kh + 8] = *(const ushort8v*)&vl[8];
    } else if constexpr (MODE == OPM_B16_COL) {
        const us* ph = (const us*)p0;
        const int m = tid & 127, kh = (tid >> 7) * 16;
        const long long base = (long long)(k0 + kh) * ld + row0 + m;
        us v[16];
        #pragma unroll
        for (int kk = 0; kk < 16; ++kk)
            v[kk] = ph[base + (long long)kk * ld];
        *(ushort8v*)&ldsH[m * LDSTRIDE + kh]     = *(const ushort8v*)&v[0];
        *(ushort8v*)&ldsH[m * LDSTRIDE + kh + 8] = *(const ushort8v*)&v[8];
    } else if constexpr (MODE == OPM_SPL_COL) {
        const us* ph = (const us*)p0;
        const us* pl = (const us*)p1;
        const int m = tid & 127, kh = (tid >> 7) * 16;
        const long long base = (long long)(k0 + kh) * ld + row0 + m;
        us vh[16], vl[16];
        #pragma unroll
        for (int kk = 0; kk < 16; ++kk) {
            vh[kk] = ph[base + (long long)kk * ld];
            vl[kk] = pl[base + (long long)kk * ld];
        }
        *(ushort8v*)&ldsH[m * LDSTRIDE + kh]     = *(const ushort8v*)&vh[0];
        *(ushort8v*)&ldsH[m * LDSTRIDE + kh + 8] = *(const ushort8v*)&vh[8];
        *(ushort8v*)&ldsL[m * LDSTRIDE + kh]     = *(const ushort8v*)&vl[0];
        *(ushort8v*)&ldsL[m * LDSTRIDE + kh + 8] = *(const ushort8v*)&vl[8];
    }
}

template<int AMODE, int BMODE, int OMODE, int EPI>
__global__ __launch_bounds__(256) void mfma_gemm(
    const void* A0, const void* A1, const void* B0, const void* B1,
    void* C0, void* C1,
    int M, int N, int K, int lda, int ldb, int ldc,
    long long sA, long long sB, long long sC,
    const float* __restrict__ bias, const float* __restrict__ invm,
    const float* __restrict__ invn, float scale)
{
    constexpr bool ASPL = (AMODE != OPM_B16_COL);
    constexpr bool BSPL = (BMODE != OPM_B16_COL);
    constexpr int ASZ = 128 * LDSTRIDE;
    __shared__ __align__(16) us Ah[ASZ];
    __shared__ __align__(16) us Al[ASPL ? ASZ : 8];
    __shared__ __align__(16) us Bh[ASZ];
    __shared__ __align__(16) us Bl[BSPL ? ASZ : 8];

    const int tid = threadIdx.x;
    const int w = tid >> 6, lane = tid & 63;
    const int quad = lane >> 4, l16 = lane & 15;
    const int m0 = blockIdx.x * 128, n0 = blockIdx.y * 128;
    const int b = blockIdx.z;

    const char* Ab0 = (const char*)A0 + (long long)b * sA;
    const char* Ab1 = A1 ? (const char*)A1 + (long long)b * sA : nullptr;
    const char* Bb0 = (const char*)B0 + (long long)b * sB;
    const char* Bb1 = B1 ? (const char*)B1 + (long long)b * sB : nullptr;

    floatx4 acc[2][8];
    #pragma unroll
    for (int mi = 0; mi < 2; ++mi)
        #pragma unroll
        for (int ni = 0; ni < 8; ++ni)
            acc[mi][ni] = (floatx4){0.f, 0.f, 0.f, 0.f};

    for (int k0 = 0; k0 < K; k0 += 32) {
        stage_tile<AMODE>(Ab0, Ab1, lda, m0, k0, Ah, Al, tid);
        stage_tile<BMODE>(Bb0, Bb1, ldb, n0, k0, Bh, Bl, tid);
        __syncthreads();

        short8v ah[2], al[2], bh[8], bl[8];
        #pragma unroll
        for (int mi = 0; mi < 2; ++mi) {
            const int r = (32 * w + 16 * mi + l16) * LDSTRIDE + quad * 8;
            ah[mi] = *(const short8v*)&Ah[r];
            if constexpr (ASPL) al[mi] = *(const short8v*)&Al[r];
        }
        #pragma unroll
        for (int ni = 0; ni < 8; ++ni) {
            const int r = (16 * ni + l16) * LDSTRIDE + quad * 8;
            bh[ni] = *(const short8v*)&Bh[r];
            if constexpr (BSPL) bl[ni] = *(const short8v*)&Bl[r];
        }
        #pragma unroll
        for (int mi = 0; mi < 2; ++mi)
            #pragma unroll
            for (int ni = 0; ni < 8; ++ni) {
                acc[mi][ni] = __builtin_amdgcn_mfma_f32_16x16x32_bf16(ah[mi], bh[ni], acc[mi][ni], 0, 0, 0);
                if constexpr (BSPL)
                    acc[mi][ni] = __builtin_amdgcn_mfma_f32_16x16x32_bf16(ah[mi], bl[ni], acc[mi][ni], 0, 0, 0);
                if constexpr (ASPL)
                    acc[mi][ni] = __builtin_amdgcn_mfma_f32_16x16x32_bf16(al[mi], bh[ni], acc[mi][ni], 0, 0, 0);
            }
        __syncthreads();
    }

    char* Cb0 = (char*)C0 + (long long)b * sC;
    char* Cb1 = C1 ? (char*)C1 + (long long)b * sC : nullptr;
    #pragma unroll
    for (int mi = 0; mi < 2; ++mi)
        #pragma unroll
        for (int ni = 0; ni < 8; ++ni)
            #pragma unroll
            for (int r = 0; r < 4; ++r) {
                const int row = m0 + 32 * w + 16 * mi + quad * 4 + r;
                const int col = n0 + 16 * ni + l16;
                float v = acc[mi][ni][r];
                if constexpr (EPI == 1) v += bias[col];
                if constexpr (EPI == 2) v *= invm[b * M + row] * invn[b * N + col] * scale;
                const long long idx = (long long)row * ldc + col;
                if constexpr (OMODE == OUT_F32) {
                    ((float*)Cb0)[idx] = v;
                } else if constexpr (OMODE == OUT_B16) {
                    ((us*)Cb0)[idx] = f2bf(v);
                } else {
                    us h, l; split_bf(v, h, l);
                    ((us*)Cb0)[idx] = h;
                    ((us*)Cb1)[idx] = l;
                }
            }
}

// =====================  small kernels  =====================

__global__ __launch_bounds__(256) void convert_w_k(
    const float* Wv, const float* Wt, us* Wvh, us* Wvl, us* Wth, us* Wtl)
{
    const int i = blockIdx.x * 256 + threadIdx.x;
    split_bf(Wv[i], Wvh[i], Wvl[i]);
    split_bf(Wt[i], Wth[i], Wtl[i]);
}

__global__ __launch_bounds__(256) void mean_img_k(
    const float* __restrict__ img, float* __restrict__ mimg)
{
    const int row = blockIdx.x * 4 + (threadIdx.x >> 6);
    const int lane = threadIdx.x & 63;
    const float* p = img + (long long)row * 1024;
    float s = 0.f;
    #pragma unroll
    for (int c = 0; c < 4; ++c) {
        float4 v = *(const float4*)&p[(c * 64 + lane) * 4];
        s += v.x + v.y + v.z + v.w;
    }
    #pragma unroll
    for (int o = 32; o > 0; o >>= 1) s += __shfl_xor(s, o);
    if (lane == 0) mimg[row] = s * (1.0f / 1024.0f);
}

__global__ __launch_bounds__(256) void mean_text_s1(
    const float* __restrict__ text, float* __restrict__ part)
{
    const int b = blockIdx.x, ch = blockIdx.y, k = threadIdx.x;
    const float* p = text + ((long long)b * 512 + ch * 64) * 256 + k;
    float s = 0.f;
    for (int r = 0; r < 64; ++r) s += p[r * 256];
    part[(b * 8 + ch) * 256 + k] = s;
}
__global__ __launch_bounds__(256) void mean_text_s2(
    const float* __restrict__ part, float* __restrict__ mt)
{
    const int b = blockIdx.x, k = threadIdx.x;
    float s = 0.f;
    for (int c = 0; c < 8; ++c) s += part[(b * 8 + c) * 256 + k];
    mt[b * 256 + k] = s * (1.0f / 512.0f);
}

__global__ __launch_bounds__(256) void small_adapter_k(
    const float* __restrict__ x, const float* __restrict__ W,
    const float* __restrict__ bias, float* __restrict__ y)
{
    const int b = blockIdx.x, d = threadIdx.x;
    __shared__ float xs[256];
    xs[d] = x[b * 256 + d];
    __syncthreads();
    const float* w = W + (long long)d * 256;
    float s = bias[d];
    for (int k = 0; k < 256; ++k) s += xs[k] * w[k];
    y[b * 256 + d] = s;
}

// ---- parallelized global loss ----

__global__ __launch_bounds__(256) void inv_norm_f32_k(
    const float* __restrict__ x, float* __restrict__ inv)
{
    const int row = blockIdx.x * 4 + (threadIdx.x >> 6);
    const int lane = threadIdx.x & 63;
    float4 v = *(const float4*)&x[(long long)row * 256 + lane * 4];
    float s = v.x * v.x + v.y * v.y + v.z * v.z + v.w * v.w;
    #pragma unroll
    for (int o = 32; o > 0; o >>= 1) s += __shfl_xor(s, o);
    if (lane == 0) inv[row] = 1.0f / fmaxf(sqrtf(s), 1e-8f);
}

__global__ __launch_bounds__(256) void g_sim_k(
    const float* __restrict__ gi, const float* __restrict__ gt,
    const float* __restrict__ invI, const float* __restrict__ invT,
    float* __restrict__ gs)
{
    const int i = blockIdx.x, t = threadIdx.x;
    const int j = t >> 2, part = t & 3;
    __shared__ float a[256];
    a[t] = gi[i * 256 + t];
    __syncthreads();
    const float* bp = gt + (long long)j * 256 + part * 64;
    const float* ap = a + part * 64;
    float s = 0.f;
    #pragma unroll 16
    for (int k = 0; k < 64; ++k) s += ap[k] * bp[k];
    s += __shfl_xor(s, 1);
    s += __shfl_xor(s, 2);
    if (part == 0) gs[i * 64 + j] = s * invI[i] * invT[j] * TAU_INV;
}

__global__ __launch_bounds__(64) void g_lse_k(
    const float* __restrict__ gs, float* __restrict__ out)
{
    const int b = blockIdx.x, lane = threadIdx.x;
    const bool is_col = b >= 64;
    const int r = is_col ? b - 64 : b;
    const float v = is_col ? gs[lane * 64 + r] : gs[r * 64 + lane];
    float m = v;
    #pragma unroll
    for (int o = 32; o > 0; o >>= 1) m = fmaxf(m, __shfl_xor(m, o));
    float s = expf(v - m);
    #pragma unroll
    for (int o = 32; o > 0; o >>= 1) s += __shfl_xor(s, o);
    if (lane == 0)
        atomicAdd(out, ((m + logf(s)) - gs[r * 64 + r]) * (0.5f / 64.0f));
}

// minmax over p of bf16 sim, stage1: grid (128, 8); stage2: grid 128
__global__ __launch_bounds__(256) void minmax_s1(
    const us* __restrict__ simW, float* __restrict__ mnp, float* __restrict__ mxp)
{
    const int bx = blockIdx.x;
    const int b = bx >> 1, s = ((bx & 1) << 8) + threadIdx.x;
    const int ch = blockIdx.y;
    const us* p = simW + ((long long)b * 1024 + ch * 128) * 512 + s;
    float lo = 1e30f, hi = -1e30f;
    for (int r = 0; r < 128; ++r) {
        const float v = bf2f(p[(long long)r * 512]);
        lo = fminf(lo, v); hi = fmaxf(hi, v);
    }
    mnp[((long long)b * 8 + ch) * 512 + s] = lo;
    mxp[((long long)b * 8 + ch) * 512 + s] = hi;
}
__global__ __launch_bounds__(256) void minmax_s2(
    const float* __restrict__ mnp, const float* __restrict__ mxp,
    float* __restrict__ mn, float* __restrict__ mx)
{
    const int bx = blockIdx.x;
    const int b = bx >> 1, s = ((bx & 1) << 8) + threadIdx.x;
    float lo = 1e30f, hi = -1e30f;
    for (int c = 0; c < 8; ++c) {
        lo = fminf(lo, mnp[((long long)b * 8 + c) * 512 + s]);
        hi = fmaxf(hi, mxp[((long long)b * 8 + c) * 512 + s]);
    }
    mn[b * 512 + s] = lo;
    mx[b * 512 + s] = hi;
}

__global__ __launch_bounds__(256) void weights_bf_k(
    us* __restrict__ simW, const float* __restrict__ mn, const float* __restrict__ mx)
{
    const long long n8 = (long long)BB * HWP * SS / 8;
    for (long long i8 = (long long)blockIdx.x * 256 + threadIdx.x; i8 < n8;
         i8 += (long long)gridDim.x * 256) {
        const long long i = i8 * 8;
        const int b = (int)(i >> 19), s0 = (int)(i & 511);
        ushort8v v = *(const ushort8v*)&simW[i];
        const float* mnb = mn + b * 512;
        const float* mxb = mx + b * 512;
        ushort8v o;
        #pragma unroll
        for (int j = 0; j < 8; ++j) {
            const float lo = mnb[s0 + j], hi = mxb[s0 + j];
            const float w = (bf2f(v[j]) - lo) / (hi - lo + 1e-8f);
            o[j] = (w < SIGMA) ? (us)0 : f2bf(w);
        }
        *(ushort8v*)&simW[i] = o;
    }
}

__global__ __launch_bounds__(256) void inv_norm_spl_k(
    const us* __restrict__ xh, const us* __restrict__ xl, float* __restrict__ inv)
{
    const int row = blockIdx.x * 4 + (threadIdx.x >> 6);
    const int lane = threadIdx.x & 63;
    ushort4 h = *(const ushort4*)&xh[(long long)row * 256 + lane * 4];
    ushort4 l = *(const ushort4*)&xl[(long long)row * 256 + lane * 4];
    const float x0 = bf2f(h.x) + bf2f(l.x), x1 = bf2f(h.y) + bf2f(l.y);
    const float x2 = bf2f(h.z) + bf2f(l.z), x3 = bf2f(h.w) + bf2f(l.w);
    float s = x0 * x0 + x1 * x1 + x2 * x2 + x3 * x3;
    #pragma unroll
    for (int o = 32; o > 0; o >>= 1) s += __shfl_xor(s, o);
    if (lane == 0) inv[row] = 1.0f / fmaxf(sqrtf(s), 1e-8f);
}

// row logsumexp - diag. R5: 512 blocks (was 8192), 16 rows/wave in registers,
// ONE atomic per block (was one per 4 rows -> 8192 same-address atomics
// serialized cross-XCD at ~13ns each = the whole 108us).
__global__ __launch_bounds__(256) void row_lse_k(
    const float* __restrict__ f, float* __restrict__ out)
{
    const int w = threadIdx.x >> 6, lane = threadIdx.x & 63;
    const int r0 = blockIdx.x * 64 + w * 16;
    float accum = 0.f;
    for (int rr = 0; rr < 16; ++rr) {
        const int r = r0 + rr;
        const float* p = f + (long long)r * SS;
        float4 v0 = *(const float4*)&p[lane * 8];
        float4 v1 = *(const float4*)&p[lane * 8 + 4];
        float vals[8] = {v0.x, v0.y, v0.z, v0.w, v1.x, v1.y, v1.z, v1.w};
        float m = vals[0];
        #pragma unroll
        for (int t = 1; t < 8; ++t) m = fmaxf(m, vals[t]);
        #pragma unroll
        for (int o = 32; o > 0; o >>= 1) m = fmaxf(m, __shfl_xor(m, o));
        float s = 0.f;
        #pragma unroll
        for (int t = 0; t < 8; ++t) s += expf(vals[t] - m);
        #pragma unroll
        for (int o = 32; o > 0; o >>= 1) s += __shfl_xor(s, o);
        accum += (m + logf(s)) - p[r & (SS - 1)];
    }
    __shared__ float red[4];
    if (lane == 0) red[w] = accum;
    __syncthreads();
    if (threadIdx.x == 0)
        atomicAdd(out, (red[0] + red[1] + red[2] + red[3]) * (0.5f / (64.0f * 512.0f)));
}

// column logsumexp - diag. R5: two-pass (max, then sum-exp) removes the
// 512-deep dependent online-softmax rescale chain; loads pipeline freely.
__global__ __launch_bounds__(256) void col_lse_k(
    const float* __restrict__ f, float* __restrict__ out)
{
    const int b = blockIdx.x >> 1;
    const int j = ((blockIdx.x & 1) << 8) + threadIdx.x;
    const float* p = f + (long long)b * SS * SS + j;
    float m = -1e30f;
    #pragma unroll 8
    for (int i = 0; i < SS; ++i) m = fmaxf(m, p[(long long)i * SS]);
    float s = 0.f;
    #pragma unroll 8
    for (int i = 0; i < SS; ++i) s += expf(p[(long long)i * SS] - m);
    const float contrib = (m + logf(s)) - p[(long long)j * SS];
    __shared__ float red[256];
    red[threadIdx.x] = contrib;
    __syncthreads();
    for (int w = 128; w > 0; w >>= 1) {
        if (threadIdx.x < w) red[threadIdx.x] += red[threadIdx.x + w];
        __syncthreads();
    }
    if (threadIdx.x == 0) atomicAdd(out, red[0] * (0.5f / (64.0f * 512.0f)));
}

extern "C" void kernel_launch(void* const* d_in, const int* in_sizes, int n_in,
                              void* d_out, int out_size, void* d_ws, size_t ws_size,
                              hipStream_t stream)
{
    const float* img  = (const float*)d_in[0];
    const float* text = (const float*)d_in[1];
    const float* Wv   = (const float*)d_in[2];
    const float* bv   = (const float*)d_in[3];
    const float* Wt   = (const float*)d_in[4];
    const float* bt   = (const float*)d_in[5];
    float* out = (float*)d_out;
    char* ws = (char*)d_ws;

    us* patches_h = (us*)(ws + 0);
    us* patches_l = (us*)(ws + 33554432);
    us* tokens_h  = (us*)(ws + 67108864);
    us* tokens_l  = (us*)(ws + 83886080);
    us* simW      = (us*)(ws + 100663296);
    float* f_sim  = (float*)(ws + 100663296);
    us* lgve_h    = (us*)(ws + 167772160);
    us* lgve_l    = (us*)(ws + 184549376);
    char* st = ws + 201326592;
    float* mean_img  = (float*)(st + 0);
    float* mean_text = (float*)(st + 65536);
    float* mean_pat  = (float*)(st + 131072);
    float* mean_tok  = (float*)(st + 196608);
    float* g_img     = (float*)(st + 262144);
    float* g_txt     = (float*)(st + 327680);
    float* textpart  = (float*)(st + 393216);
    float* mnp       = (float*)(st + 917504);
    float* mxp       = (float*)(st + 1966080);
    float* mnv       = (float*)(st + 3014656);
    float* mxv       = (float*)(st + 3145728);
    float* inv_l     = (float*)(st + 3276800);
    float* inv_t     = (float*)(st + 3407872);
    us* Wvh = (us*)(st + 3538944);
    us* Wvl = (us*)(st + 3670016);
    us* Wth = (us*)(st + 3801088);
    us* Wtl = (us*)(st + 3932160);
    float* inv_gi  = (float*)(st + 4063232);
    float* inv_gt  = (float*)(st + 4063744);
    float* g_simbf = (float*)(st + 4064256);

    zero_out_k<<<1, 64, 0, stream>>>(out);
    convert_w_k<<<256, 256, 0, stream>>>(Wv, Wt, Wvh, Wvl, Wth, Wtl);

    // Global path (mean commutes with linear)
    mean_img_k<<<4096, 256, 0, stream>>>(img, mean_img);
    mean_text_s1<<<dim3(64, 8), 256, 0, stream>>>(text, textpart);
    mean_text_s2<<<64, 256, 0, stream>>>(textpart, mean_text);
    small_adapter_k<<<BB, 256, 0, stream>>>(mean_img, Wv, bv, mean_pat);
    small_adapter_k<<<BB, 256, 0, stream>>>(mean_pat, Wv, bv, g_img);
    small_adapter_k<<<BB, 256, 0, stream>>>(mean_text, Wt, bt, mean_tok);
    small_adapter_k<<<BB, 256, 0, stream>>>(mean_tok, Wt, bt, g_txt);
    inv_norm_f32_k<<<16, 256, 0, stream>>>(g_img, inv_gi);
    inv_norm_f32_k<<<16, 256, 0, stream>>>(g_txt, inv_gt);
    g_sim_k<<<64, 256, 0, stream>>>(g_img, g_txt, inv_gi, inv_gt, g_simbf);
    g_lse_k<<<128, 64, 0, stream>>>(g_simbf, out);

    // G1: patches
    mfma_gemm<OPM_F32_COL, OPM_SPL_ROW, OUT_SPL, 1><<<dim3(8, 2, BB), 256, 0, stream>>>(
        img, nullptr, Wvh, Wvl, patches_h, patches_l,
        1024, 256, 256, 1024, 256, 256,
        1048576LL, 0LL, 524288LL, bv, nullptr, nullptr, 0.f);

    // G2: tokens
    mfma_gemm<OPM_F32_ROW, OPM_SPL_ROW, OUT_SPL, 1><<<dim3(4, 2, BB), 256, 0, stream>>>(
        text, nullptr, Wth, Wtl, tokens_h, tokens_l,
        512, 256, 256, 256, 256, 256,
        524288LL, 0LL, 262144LL, bt, nullptr, nullptr, 0.f);

    // G4: sim -> bf16
    mfma_gemm<OPM_SPL_ROW, OPM_SPL_ROW, OUT_B16, 0><<<dim3(8, 4, BB), 256, 0, stream>>>(
        patches_h, patches_l, tokens_h, tokens_l, simW, nullptr,
        1024, 512, 256, 256, 256, 512,
        524288LL, 262144LL, 1048576LL, nullptr, nullptr, nullptr, 0.f);

    // min-max + threshold weights (in-place bf16)
    minmax_s1<<<dim3(128, 8), 256, 0, stream>>>(simW, mnp, mxp);
    minmax_s2<<<128, 256, 0, stream>>>(mnp, mxp, mnv, mxv);
    weights_bf_k<<<4096, 256, 0, stream>>>(simW, mnv, mxv);

    // G6: lgve (L1 norm dropped: positive row scale cancels in later L2 norm)
    mfma_gemm<OPM_B16_COL, OPM_SPL_COL, OUT_SPL, 0><<<dim3(4, 2, BB), 256, 0, stream>>>(
        simW, nullptr, patches_h, patches_l, lgve_h, lgve_l,
        512, 256, 1024, 512, 256, 256,
        1048576LL, 524288LL, 262144LL, nullptr, nullptr, nullptr, 0.f);

    // inverse L2 norms
    inv_norm_spl_k<<<8192, 256, 0, stream>>>(lgve_h, lgve_l, inv_l);
    inv_norm_spl_k<<<8192, 256, 0, stream>>>(tokens_h, tokens_l, inv_t);

    // G8: f_sim -> fp32 with cos epilogue
    mfma_gemm<OPM_SPL_ROW, OPM_SPL_ROW, OUT_F32, 2><<<dim3(4, 4, BB), 256, 0, stream>>>(
        lgve_h, lgve_l, tokens_h, tokens_l, f_sim, nullptr,
        512, 512, 256, 256, 256, 512,
        262144LL, 262144LL, 1048576LL, nullptr, inv_l, inv_t, TAU_INV);

    // fine-grained symmetric CE
    row_lse_k<<<512, 256, 0, stream>>>(f_sim, out);
    col_lse_k<<<128, 256, 0, stream>>>(f_sim, out);
}

// Round 7
// 547.702 us; speedup vs baseline: 2.9327x; 1.1626x over previous
//
#include <hip/hip_runtime.h>
#include <math.h>

#define BB   64
#define HWP  1024
#define SS   512
#define DD   256
#define TAU_INV (1.0f/0.07f)
#define SIGMA   (1.0f/1024.0f)

typedef unsigned short us;
typedef __attribute__((ext_vector_type(8))) short short8v;
typedef __attribute__((ext_vector_type(8))) unsigned short ushort8v;
typedef __attribute__((ext_vector_type(4))) float floatx4;

__device__ __forceinline__ float bf2f(us u) {
    return __uint_as_float((unsigned)u << 16);
}
__device__ __forceinline__ us f2bf(float f) {
    unsigned u = __float_as_uint(f);
    u += 0x7FFFu + ((u >> 16) & 1u);
    return (us)(u >> 16);
}
__device__ __forceinline__ void split_bf(float v, us& h, us& l) {
    h = f2bf(v);
    l = f2bf(v - bf2f(h));
}

__global__ void zero_out_k(float* out) { if (threadIdx.x == 0) out[0] = 0.0f; }

// =====================  MFMA GEMM  =====================
// C[m,n] = sum_k A(m,k)*B(n,k), 128x128 tile, BK=32, 16x16x32 bf16 MFMA,
// split-bf16 operands (hi+lo): AB ~= AhBh + AhBl + AlBh.
enum { OPM_F32_ROW = 0, OPM_F32_COL = 1, OPM_SPL_ROW = 2, OPM_SPL_COL = 3,
       OPM_B16_COL = 4 };
enum { OUT_F32 = 0, OUT_B16 = 1, OUT_SPL = 2 };

#define LDSTRIDE 40

// COL staging: thread-per-m register gather, b128 row stores (conflict-free).
template<int MODE>
__device__ __forceinline__ void stage_tile(
    const char* p0, const char* p1, int ld, int row0, int k0,
    us* ldsH, us* ldsL, int tid)
{
    if constexpr (MODE == OPM_SPL_ROW) {
        const us* ph = (const us*)p0;
        const us* pl = (const us*)p1;
        const int i = tid >> 1, ko = (tid & 1) * 16;
        const long long g = (long long)(row0 + i) * ld + k0 + ko;
        *(ushort8v*)&ldsH[i * LDSTRIDE + ko]     = *(const ushort8v*)&ph[g];
        *(ushort8v*)&ldsH[i * LDSTRIDE + ko + 8] = *(const ushort8v*)&ph[g + 8];
        *(ushort8v*)&ldsL[i * LDSTRIDE + ko]     = *(const ushort8v*)&pl[g];
        *(ushort8v*)&ldsL[i * LDSTRIDE + ko + 8] = *(const ushort8v*)&pl[g + 8];
    } else if constexpr (MODE == OPM_F32_ROW) {
        const float* pf = (const float*)p0;
        const int i = tid >> 1, ko = (tid & 1) * 16;
        const long long g = (long long)(row0 + i) * ld + k0 + ko;
        us h16[16], l16[16];
        #pragma unroll
        for (int c = 0; c < 16; c += 4) {
            float4 v = *(const float4*)&pf[g + c];
            split_bf(v.x, h16[c+0], l16[c+0]); split_bf(v.y, h16[c+1], l16[c+1]);
            split_bf(v.z, h16[c+2], l16[c+2]); split_bf(v.w, h16[c+3], l16[c+3]);
        }
        *(ushort8v*)&ldsH[i * LDSTRIDE + ko]     = *(const ushort8v*)&h16[0];
        *(ushort8v*)&ldsH[i * LDSTRIDE + ko + 8] = *(const ushort8v*)&h16[8];
        *(ushort8v*)&ldsL[i * LDSTRIDE + ko]     = *(const ushort8v*)&l16[0];
        *(ushort8v*)&ldsL[i * LDSTRIDE + ko + 8] = *(const ushort8v*)&l16[8];
    } else if constexpr (MODE == OPM_F32_COL) {
        const float* pf = (const float*)p0;
        const int m = tid & 127, kh = (tid >> 7) * 16;
        const long long base = (long long)(k0 + kh) * ld + row0 + m;
        us vh[16], vl[16];
        #pragma unroll
        for (int kk = 0; kk < 16; ++kk)
            split_bf(pf[base + (long long)kk * ld], vh[kk], vl[kk]);
        *(ushort8v*)&ldsH[m * LDSTRIDE + kh]     = *(const ushort8v*)&vh[0];
        *(ushort8v*)&ldsH[m * LDSTRIDE + kh + 8] = *(const ushort8v*)&vh[8];
        *(ushort8v*)&ldsL[m * LDSTRIDE + kh]     = *(const ushort8v*)&vl[0];
        *(ushort8v*)&ldsL[m * LDSTRIDE + kh + 8] = *(const ushort8v*)&vl[8];
    } else if constexpr (MODE == OPM_B16_COL) {
        const us* ph = (const us*)p0;
        const int m = tid & 127, kh = (tid >> 7) * 16;
        const long long base = (long long)(k0 + kh) * ld + row0 + m;
        us v[16];
        #pragma unroll
        for (int kk = 0; kk < 16; ++kk)
            v[kk] = ph[base + (long long)kk * ld];
        *(ushort8v*)&ldsH[m * LDSTRIDE + kh]     = *(const ushort8v*)&v[0];
        *(ushort8v*)&ldsH[m * LDSTRIDE + kh + 8] = *(const ushort8v*)&v[8];
    } else if constexpr (MODE == OPM_SPL_COL) {
        const us* ph = (const us*)p0;
        const us* pl = (const us*)p1;
        const int m = tid & 127, kh = (tid >> 7) * 16;
        const long long base = (long long)(k0 + kh) * ld + row0 + m;
        us vh[16], vl[16];
        #pragma unroll
        for (int kk = 0; kk < 16; ++kk) {
            vh[kk] = ph[base + (long long)kk * ld];
            vl[kk] = pl[base + (long long)kk * ld];
        }
        *(ushort8v*)&ldsH[m * LDSTRIDE + kh]     = *(const ushort8v*)&vh[0];
        *(ushort8v*)&ldsH[m * LDSTRIDE + kh + 8] = *(const ushort8v*)&vh[8];
        *(ushort8v*)&ldsL[m * LDSTRIDE + kh]     = *(const ushort8v*)&vl[0];
        *(ushort8v*)&ldsL[m * LDSTRIDE + kh + 8] = *(const ushort8v*)&vl[8];
    }
}

template<int AMODE, int BMODE, int OMODE, int EPI>
__global__ __launch_bounds__(256) void mfma_gemm(
    const void* A0, const void* A1, const void* B0, const void* B1,
    void* C0, void* C1,
    int M, int N, int K, int lda, int ldb, int ldc,
    long long sA, long long sB, long long sC,
    const float* __restrict__ bias, const float* __restrict__ invm,
    const float* __restrict__ invn, float scale)
{
    constexpr bool ASPL = (AMODE != OPM_B16_COL);
    constexpr bool BSPL = (BMODE != OPM_B16_COL);
    constexpr int ASZ = 128 * LDSTRIDE;
    __shared__ __align__(16) us Ah[ASZ];
    __shared__ __align__(16) us Al[ASPL ? ASZ : 8];
    __shared__ __align__(16) us Bh[ASZ];
    __shared__ __align__(16) us Bl[BSPL ? ASZ : 8];

    const int tid = threadIdx.x;
    const int w = tid >> 6, lane = tid & 63;
    const int quad = lane >> 4, l16 = lane & 15;
    const int m0 = blockIdx.x * 128, n0 = blockIdx.y * 128;
    const int b = blockIdx.z;

    const char* Ab0 = (const char*)A0 + (long long)b * sA;
    const char* Ab1 = A1 ? (const char*)A1 + (long long)b * sA : nullptr;
    const char* Bb0 = (const char*)B0 + (long long)b * sB;
    const char* Bb1 = B1 ? (const char*)B1 + (long long)b * sB : nullptr;

    floatx4 acc[2][8];
    #pragma unroll
    for (int mi = 0; mi < 2; ++mi)
        #pragma unroll
        for (int ni = 0; ni < 8; ++ni)
            acc[mi][ni] = (floatx4){0.f, 0.f, 0.f, 0.f};

    for (int k0 = 0; k0 < K; k0 += 32) {
        stage_tile<AMODE>(Ab0, Ab1, lda, m0, k0, Ah, Al, tid);
        stage_tile<BMODE>(Bb0, Bb1, ldb, n0, k0, Bh, Bl, tid);
        __syncthreads();

        short8v ah[2], al[2], bh[8], bl[8];
        #pragma unroll
        for (int mi = 0; mi < 2; ++mi) {
            const int r = (32 * w + 16 * mi + l16) * LDSTRIDE + quad * 8;
            ah[mi] = *(const short8v*)&Ah[r];
            if constexpr (ASPL) al[mi] = *(const short8v*)&Al[r];
        }
        #pragma unroll
        for (int ni = 0; ni < 8; ++ni) {
            const int r = (16 * ni + l16) * LDSTRIDE + quad * 8;
            bh[ni] = *(const short8v*)&Bh[r];
            if constexpr (BSPL) bl[ni] = *(const short8v*)&Bl[r];
        }
        #pragma unroll
        for (int mi = 0; mi < 2; ++mi)
            #pragma unroll
            for (int ni = 0; ni < 8; ++ni) {
                acc[mi][ni] = __builtin_amdgcn_mfma_f32_16x16x32_bf16(ah[mi], bh[ni], acc[mi][ni], 0, 0, 0);
                if constexpr (BSPL)
                    acc[mi][ni] = __builtin_amdgcn_mfma_f32_16x16x32_bf16(ah[mi], bl[ni], acc[mi][ni], 0, 0, 0);
                if constexpr (ASPL)
                    acc[mi][ni] = __builtin_amdgcn_mfma_f32_16x16x32_bf16(al[mi], bh[ni], acc[mi][ni], 0, 0, 0);
            }
        __syncthreads();
    }

    char* Cb0 = (char*)C0 + (long long)b * sC;
    char* Cb1 = C1 ? (char*)C1 + (long long)b * sC : nullptr;
    #pragma unroll
    for (int mi = 0; mi < 2; ++mi)
        #pragma unroll
        for (int ni = 0; ni < 8; ++ni)
            #pragma unroll
            for (int r = 0; r < 4; ++r) {
                const int row = m0 + 32 * w + 16 * mi + quad * 4 + r;
                const int col = n0 + 16 * ni + l16;
                float v = acc[mi][ni][r];
                if constexpr (EPI == 1) v += bias[col];
                if constexpr (EPI == 2) v *= invm[b * M + row] * invn[b * N + col] * scale;
                const long long idx = (long long)row * ldc + col;
                if constexpr (OMODE == OUT_F32) {
                    ((float*)Cb0)[idx] = v;
                } else if constexpr (OMODE == OUT_B16) {
                    ((us*)Cb0)[idx] = f2bf(v);
                } else {
                    us h, l; split_bf(v, h, l);
                    ((us*)Cb0)[idx] = h;
                    ((us*)Cb1)[idx] = l;
                }
            }
}

// =====================  small kernels  =====================

__global__ __launch_bounds__(256) void convert_w_k(
    const float* Wv, const float* Wt, us* Wvh, us* Wvl, us* Wth, us* Wtl)
{
    const int i = blockIdx.x * 256 + threadIdx.x;
    split_bf(Wv[i], Wvh[i], Wvl[i]);
    split_bf(Wt[i], Wth[i], Wtl[i]);
}

__global__ __launch_bounds__(256) void mean_img_k(
    const float* __restrict__ img, float* __restrict__ mimg)
{
    const int row = blockIdx.x * 4 + (threadIdx.x >> 6);
    const int lane = threadIdx.x & 63;
    const float* p = img + (long long)row * 1024;
    float s = 0.f;
    #pragma unroll
    for (int c = 0; c < 4; ++c) {
        float4 v = *(const float4*)&p[(c * 64 + lane) * 4];
        s += v.x + v.y + v.z + v.w;
    }
    #pragma unroll
    for (int o = 32; o > 0; o >>= 1) s += __shfl_xor(s, o);
    if (lane == 0) mimg[row] = s * (1.0f / 1024.0f);
}

__global__ __launch_bounds__(256) void mean_text_s1(
    const float* __restrict__ text, float* __restrict__ part)
{
    const int b = blockIdx.x, ch = blockIdx.y, k = threadIdx.x;
    const float* p = text + ((long long)b * 512 + ch * 64) * 256 + k;
    float s = 0.f;
    for (int r = 0; r < 64; ++r) s += p[r * 256];
    part[(b * 8 + ch) * 256 + k] = s;
}
__global__ __launch_bounds__(256) void mean_text_s2(
    const float* __restrict__ part, float* __restrict__ mt)
{
    const int b = blockIdx.x, k = threadIdx.x;
    float s = 0.f;
    for (int c = 0; c < 8; ++c) s += part[(b * 8 + c) * 256 + k];
    mt[b * 256 + k] = s * (1.0f / 512.0f);
}

__global__ __launch_bounds__(256) void small_adapter_k(
    const float* __restrict__ x, const float* __restrict__ W,
    const float* __restrict__ bias, float* __restrict__ y)
{
    const int b = blockIdx.x, d = threadIdx.x;
    __shared__ float xs[256];
    xs[d] = x[b * 256 + d];
    __syncthreads();
    const float* w = W + (long long)d * 256;
    float s = bias[d];
    for (int k = 0; k < 256; ++k) s += xs[k] * w[k];
    y[b * 256 + d] = s;
}

// ---- parallelized global loss ----

__global__ __launch_bounds__(256) void inv_norm_f32_k(
    const float* __restrict__ x, float* __restrict__ inv)
{
    const int row = blockIdx.x * 4 + (threadIdx.x >> 6);
    const int lane = threadIdx.x & 63;
    float4 v = *(const float4*)&x[(long long)row * 256 + lane * 4];
    float s = v.x * v.x + v.y * v.y + v.z * v.z + v.w * v.w;
    #pragma unroll
    for (int o = 32; o > 0; o >>= 1) s += __shfl_xor(s, o);
    if (lane == 0) inv[row] = 1.0f / fmaxf(sqrtf(s), 1e-8f);
}

__global__ __launch_bounds__(256) void g_sim_k(
    const float* __restrict__ gi, const float* __restrict__ gt,
    const float* __restrict__ invI, const float* __restrict__ invT,
    float* __restrict__ gs)
{
    const int i = blockIdx.x, t = threadIdx.x;
    const int j = t >> 2, part = t & 3;
    __shared__ float a[256];
    a[t] = gi[i * 256 + t];
    __syncthreads();
    const float* bp = gt + (long long)j * 256 + part * 64;
    const float* ap = a + part * 64;
    float s = 0.f;
    #pragma unroll 16
    for (int k = 0; k < 64; ++k) s += ap[k] * bp[k];
    s += __shfl_xor(s, 1);
    s += __shfl_xor(s, 2);
    if (part == 0) gs[i * 64 + j] = s * invI[i] * invT[j] * TAU_INV;
}

__global__ __launch_bounds__(64) void g_lse_k(
    const float* __restrict__ gs, float* __restrict__ out)
{
    const int b = blockIdx.x, lane = threadIdx.x;
    const bool is_col = b >= 64;
    const int r = is_col ? b - 64 : b;
    const float v = is_col ? gs[lane * 64 + r] : gs[r * 64 + lane];
    float m = v;
    #pragma unroll
    for (int o = 32; o > 0; o >>= 1) m = fmaxf(m, __shfl_xor(m, o));
    float s = expf(v - m);
    #pragma unroll
    for (int o = 32; o > 0; o >>= 1) s += __shfl_xor(s, o);
    if (lane == 0)
        atomicAdd(out, ((m + logf(s)) - gs[r * 64 + r]) * (0.5f / 64.0f));
}

// minmax over p of bf16 sim, stage1: grid (128, 8); stage2: grid 128
__global__ __launch_bounds__(256) void minmax_s1(
    const us* __restrict__ simW, float* __restrict__ mnp, float* __restrict__ mxp)
{
    const int bx = blockIdx.x;
    const int b = bx >> 1, s = ((bx & 1) << 8) + threadIdx.x;
    const int ch = blockIdx.y;
    const us* p = simW + ((long long)b * 1024 + ch * 128) * 512 + s;
    float lo = 1e30f, hi = -1e30f;
    for (int r = 0; r < 128; ++r) {
        const float v = bf2f(p[(long long)r * 512]);
        lo = fminf(lo, v); hi = fmaxf(hi, v);
    }
    mnp[((long long)b * 8 + ch) * 512 + s] = lo;
    mxp[((long long)b * 8 + ch) * 512 + s] = hi;
}
__global__ __launch_bounds__(256) void minmax_s2(
    const float* __restrict__ mnp, const float* __restrict__ mxp,
    float* __restrict__ mn, float* __restrict__ mx)
{
    const int bx = blockIdx.x;
    const int b = bx >> 1, s = ((bx & 1) << 8) + threadIdx.x;
    float lo = 1e30f, hi = -1e30f;
    for (int c = 0; c < 8; ++c) {
        lo = fminf(lo, mnp[((long long)b * 8 + c) * 512 + s]);
        hi = fmaxf(hi, mxp[((long long)b * 8 + c) * 512 + s]);
    }
    mn[b * 512 + s] = lo;
    mx[b * 512 + s] = hi;
}

__global__ __launch_bounds__(256) void weights_bf_k(
    us* __restrict__ simW, const float* __restrict__ mn, const float* __restrict__ mx)
{
    const long long n8 = (long long)BB * HWP * SS / 8;
    for (long long i8 = (long long)blockIdx.x * 256 + threadIdx.x; i8 < n8;
         i8 += (long long)gridDim.x * 256) {
        const long long i = i8 * 8;
        const int b = (int)(i >> 19), s0 = (int)(i & 511);
        ushort8v v = *(const ushort8v*)&simW[i];
        const float* mnb = mn + b * 512;
        const float* mxb = mx + b * 512;
        ushort8v o;
        #pragma unroll
        for (int j = 0; j < 8; ++j) {
            const float lo = mnb[s0 + j], hi = mxb[s0 + j];
            const float w = (bf2f(v[j]) - lo) / (hi - lo + 1e-8f);
            o[j] = (w < SIGMA) ? (us)0 : f2bf(w);
        }
        *(ushort8v*)&simW[i] = o;
    }
}

__global__ __launch_bounds__(256) void inv_norm_spl_k(
    const us* __restrict__ xh, const us* __restrict__ xl, float* __restrict__ inv)
{
    const int row = blockIdx.x * 4 + (threadIdx.x >> 6);
    const int lane = threadIdx.x & 63;
    ushort4 h = *(const ushort4*)&xh[(long long)row * 256 + lane * 4];
    ushort4 l = *(const ushort4*)&xl[(long long)row * 256 + lane * 4];
    const float x0 = bf2f(h.x) + bf2f(l.x), x1 = bf2f(h.y) + bf2f(l.y);
    const float x2 = bf2f(h.z) + bf2f(l.z), x3 = bf2f(h.w) + bf2f(l.w);
    float s = x0 * x0 + x1 * x1 + x2 * x2 + x3 * x3;
    #pragma unroll
    for (int o = 32; o > 0; o >>= 1) s += __shfl_xor(s, o);
    if (lane == 0) inv[row] = 1.0f / fmaxf(sqrtf(s), 1e-8f);
}

// row logsumexp - diag: 512 blocks, 16 rows/wave, one atomic per block.
__global__ __launch_bounds__(256) void row_lse_k(
    const float* __restrict__ f, float* __restrict__ out)
{
    const int w = threadIdx.x >> 6, lane = threadIdx.x & 63;
    const int r0 = blockIdx.x * 64 + w * 16;
    float accum = 0.f;
    for (int rr = 0; rr < 16; ++rr) {
        const int r = r0 + rr;
        const float* p = f + (long long)r * SS;
        float4 v0 = *(const float4*)&p[lane * 8];
        float4 v1 = *(const float4*)&p[lane * 8 + 4];
        float vals[8] = {v0.x, v0.y, v0.z, v0.w, v1.x, v1.y, v1.z, v1.w};
        float m = vals[0];
        #pragma unroll
        for (int t = 1; t < 8; ++t) m = fmaxf(m, vals[t]);
        #pragma unroll
        for (int o = 32; o > 0; o >>= 1) m = fmaxf(m, __shfl_xor(m, o));
        float s = 0.f;
        #pragma unroll
        for (int t = 0; t < 8; ++t) s += expf(vals[t] - m);
        #pragma unroll
        for (int o = 32; o > 0; o >>= 1) s += __shfl_xor(s, o);
        accum += (m + logf(s)) - p[r & (SS - 1)];
    }
    __shared__ float red[4];
    if (lane == 0) red[w] = accum;
    __syncthreads();
    if (threadIdx.x == 0)
        atomicAdd(out, (red[0] + red[1] + red[2] + red[3]) * (0.5f / (64.0f * 512.0f)));
}

// R6: two-stage column LSE (was 128 blocks @ 2 serial passes = 120us,
// 5% occupancy, half the CUs idle).
// Stage 1: grid (B, 8) = 512 blocks; each block owns 64 rows x 512 cols,
// each thread online-softmaxes 2 columns with coalesced float2 row reads.
__global__ __launch_bounds__(256) void col_lse_s1(
    const float* __restrict__ f, float* __restrict__ pm, float* __restrict__ ps)
{
    const int b = blockIdx.x, ch = blockIdx.y;
    const float* base = f + (long long)b * SS * SS + (long long)ch * 64 * SS;
    const int c0 = threadIdx.x * 2;
    float m0 = -1e30f, m1 = -1e30f, s0 = 0.f, s1 = 0.f;
    #pragma unroll 4
    for (int r = 0; r < 64; ++r) {
        const float2 v = *(const float2*)&base[r * SS + c0];
        const float nm0 = fmaxf(m0, v.x);
        s0 = s0 * expf(m0 - nm0) + expf(v.x - nm0);
        m0 = nm0;
        const float nm1 = fmaxf(m1, v.y);
        s1 = s1 * expf(m1 - nm1) + expf(v.y - nm1);
        m1 = nm1;
    }
    const long long o = ((long long)b * 8 + ch) * SS + c0;
    *(float2*)&pm[o] = make_float2(m0, m1);
    *(float2*)&ps[o] = make_float2(s0, s1);
}
// Stage 2: grid 128; merge 8 chunk partials per column, subtract diag, reduce.
__global__ __launch_bounds__(256) void col_lse_s2(
    const float* __restrict__ pm, const float* __restrict__ ps,
    const float* __restrict__ f, float* __restrict__ out)
{
    const int b = blockIdx.x >> 1;
    const int j = ((blockIdx.x & 1) << 8) + threadIdx.x;
    float m = -1e30f, s = 0.f;
    #pragma unroll
    for (int c = 0; c < 8; ++c) {
        const long long o = ((long long)b * 8 + c) * SS + j;
        const float cm = pm[o], cs = ps[o];
        const float nm = fmaxf(m, cm);
        s = s * expf(m - nm) + cs * expf(cm - nm);
        m = nm;
    }
    const float contrib = (m + logf(s)) - f[(long long)b * SS * SS + (long long)j * SS + j];
    __shared__ float red[256];
    red[threadIdx.x] = contrib;
    __syncthreads();
    for (int w = 128; w > 0; w >>= 1) {
        if (threadIdx.x < w) red[threadIdx.x] += red[threadIdx.x + w];
        __syncthreads();
    }
    if (threadIdx.x == 0) atomicAdd(out, red[0] * (0.5f / (64.0f * 512.0f)));
}

extern "C" void kernel_launch(void* const* d_in, const int* in_sizes, int n_in,
                              void* d_out, int out_size, void* d_ws, size_t ws_size,
                              hipStream_t stream)
{
    const float* img  = (const float*)d_in[0];
    const float* text = (const float*)d_in[1];
    const float* Wv   = (const float*)d_in[2];
    const float* bv   = (const float*)d_in[3];
    const float* Wt   = (const float*)d_in[4];
    const float* bt   = (const float*)d_in[5];
    float* out = (float*)d_out;
    char* ws = (char*)d_ws;

    us* patches_h = (us*)(ws + 0);
    us* patches_l = (us*)(ws + 33554432);
    us* tokens_h  = (us*)(ws + 67108864);
    us* tokens_l  = (us*)(ws + 83886080);
    us* simW      = (us*)(ws + 100663296);
    float* f_sim  = (float*)(ws + 100663296);
    us* lgve_h    = (us*)(ws + 167772160);
    us* lgve_l    = (us*)(ws + 184549376);
    char* st = ws + 201326592;
    float* mean_img  = (float*)(st + 0);
    float* mean_text = (float*)(st + 65536);
    float* mean_pat  = (float*)(st + 131072);
    float* mean_tok  = (float*)(st + 196608);
    float* g_img     = (float*)(st + 262144);
    float* g_txt     = (float*)(st + 327680);
    float* textpart  = (float*)(st + 393216);
    float* mnp       = (float*)(st + 917504);
    float* mxp       = (float*)(st + 1966080);
    float* mnv       = (float*)(st + 3014656);
    float* mxv       = (float*)(st + 3145728);
    float* inv_l     = (float*)(st + 3276800);
    float* inv_t     = (float*)(st + 3407872);
    us* Wvh = (us*)(st + 3538944);
    us* Wvl = (us*)(st + 3670016);
    us* Wth = (us*)(st + 3801088);
    us* Wtl = (us*)(st + 3932160);
    float* inv_gi  = (float*)(st + 4063232);
    float* inv_gt  = (float*)(st + 4063744);
    float* g_simbf = (float*)(st + 4064256);
    float* col_pm  = (float*)(st + 4194304);   // 64*8*512 f32 = 1 MB
    float* col_ps  = (float*)(st + 5242880);   // 1 MB

    zero_out_k<<<1, 64, 0, stream>>>(out);
    convert_w_k<<<256, 256, 0, stream>>>(Wv, Wt, Wvh, Wvl, Wth, Wtl);

    // Global path (mean commutes with linear)
    mean_img_k<<<4096, 256, 0, stream>>>(img, mean_img);
    mean_text_s1<<<dim3(64, 8), 256, 0, stream>>>(text, textpart);
    mean_text_s2<<<64, 256, 0, stream>>>(textpart, mean_text);
    small_adapter_k<<<BB, 256, 0, stream>>>(mean_img, Wv, bv, mean_pat);
    small_adapter_k<<<BB, 256, 0, stream>>>(mean_pat, Wv, bv, g_img);
    small_adapter_k<<<BB, 256, 0, stream>>>(mean_text, Wt, bt, mean_tok);
    small_adapter_k<<<BB, 256, 0, stream>>>(mean_tok, Wt, bt, g_txt);
    inv_norm_f32_k<<<16, 256, 0, stream>>>(g_img, inv_gi);
    inv_norm_f32_k<<<16, 256, 0, stream>>>(g_txt, inv_gt);
    g_sim_k<<<64, 256, 0, stream>>>(g_img, g_txt, inv_gi, inv_gt, g_simbf);
    g_lse_k<<<128, 64, 0, stream>>>(g_simbf, out);

    // G1: patches
    mfma_gemm<OPM_F32_COL, OPM_SPL_ROW, OUT_SPL, 1><<<dim3(8, 2, BB), 256, 0, stream>>>(
        img, nullptr, Wvh, Wvl, patches_h, patches_l,
        1024, 256, 256, 1024, 256, 256,
        1048576LL, 0LL, 524288LL, bv, nullptr, nullptr, 0.f);

    // G2: tokens
    mfma_gemm<OPM_F32_ROW, OPM_SPL_ROW, OUT_SPL, 1><<<dim3(4, 2, BB), 256, 0, stream>>>(
        text, nullptr, Wth, Wtl, tokens_h, tokens_l,
        512, 256, 256, 256, 256, 256,
        524288LL, 0LL, 262144LL, bt, nullptr, nullptr, 0.f);

    // G4: sim -> bf16
    mfma_gemm<OPM_SPL_ROW, OPM_SPL_ROW, OUT_B16, 0><<<dim3(8, 4, BB), 256, 0, stream>>>(
        patches_h, patches_l, tokens_h, tokens_l, simW, nullptr,
        1024, 512, 256, 256, 256, 512,
        524288LL, 262144LL, 1048576LL, nullptr, nullptr, nullptr, 0.f);

    // min-max + threshold weights (in-place bf16)
    minmax_s1<<<dim3(128, 8), 256, 0, stream>>>(simW, mnp, mxp);
    minmax_s2<<<128, 256, 0, stream>>>(mnp, mxp, mnv, mxv);
    weights_bf_k<<<4096, 256, 0, stream>>>(simW, mnv, mxv);

    // G6: lgve (L1 norm dropped: positive row scale cancels in later L2 norm)
    mfma_gemm<OPM_B16_COL, OPM_SPL_COL, OUT_SPL, 0><<<dim3(4, 2, BB), 256, 0, stream>>>(
        simW, nullptr, patches_h, patches_l, lgve_h, lgve_l,
        512, 256, 1024, 512, 256, 256,
        1048576LL, 524288LL, 262144LL, nullptr, nullptr, nullptr, 0.f);

    // inverse L2 norms
    inv_norm_spl_k<<<8192, 256, 0, stream>>>(lgve_h, lgve_l, inv_l);
    inv_norm_spl_k<<<8192, 256, 0, stream>>>(tokens_h, tokens_l, inv_t);

    // G8: f_sim -> fp32 with cos epilogue
    mfma_gemm<OPM_SPL_ROW, OPM_SPL_ROW, OUT_F32, 2><<<dim3(4, 4, BB), 256, 0, stream>>>(
        lgve_h, lgve_l, tokens_h, tokens_l, f_sim, nullptr,
        512, 512, 256, 256, 256, 512,
        262144LL, 262144LL, 1048576LL, nullptr, inv_l, inv_t, TAU_INV);

    // fine-grained symmetric CE
    row_lse_k<<<512, 256, 0, stream>>>(f_sim, out);
    col_lse_s1<<<dim3(BB, 8), 256, 0, stream>>>(f_sim, col_pm, col_ps);
    col_lse_s2<<<128, 256, 0, stream>>>(col_pm, col_ps, f_sim, out);
}

// Round 8
// 433.273 us; speedup vs baseline: 3.7073x; 1.2641x over previous
//
#include <hip/hip_runtime.h>
#include <math.h>

#define BB   64
#define HWP  1024
#define SS   512
#define DD   256
#define TAU_INV (1.0f/0.07f)
#define SIGMA   (1.0f/1024.0f)

typedef unsigned short us;
typedef __attribute__((ext_vector_type(8))) short short8v;
typedef __attribute__((ext_vector_type(8))) unsigned short ushort8v;
typedef __attribute__((ext_vector_type(4))) float floatx4;

__device__ __forceinline__ float bf2f(us u) {
    return __uint_as_float((unsigned)u << 16);
}
__device__ __forceinline__ us f2bf(float f) {
    unsigned u = __float_as_uint(f);
    u += 0x7FFFu + ((u >> 16) & 1u);
    return (us)(u >> 16);
}
__device__ __forceinline__ void split_bf(float v, us& h, us& l) {
    h = f2bf(v);
    l = f2bf(v - bf2f(h));
}

__global__ void zero_out_k(float* out) { if (threadIdx.x == 0) out[0] = 0.0f; }

// =====================  MFMA GEMM  =====================
// C[m,n] = sum_k A(m,k)*B(n,k), 128x128 tile, BK=32, 16x16x32 bf16 MFMA.
// Split modes (0-3) carry hi+lo bf16 for ~fp32 accuracy (3 mfma/pair);
// single modes (4-6) are plain bf16 (1 mfma/pair). R7: everything downstream
// of the adapters is single-bf16 (storage quantization dominates anyway).
enum { OPM_F32_ROW = 0, OPM_F32_COL = 1, OPM_SPL_ROW = 2, OPM_SPL_COL = 3,
       OPM_B16_COL = 4, OPM_B16_ROW = 5, OPM_WGT_COL = 6 };
enum { OUT_F32 = 0, OUT_B16 = 1 };

#define LDSTRIDE 40

template<int MODE>
__device__ __forceinline__ void stage_tile(
    const char* p0, const char* p1, int ld, int row0, int k0,
    us* ldsH, us* ldsL, int tid,
    const float* wlo, const float* whi)
{
    if constexpr (MODE == OPM_SPL_ROW) {
        const us* ph = (const us*)p0;
        const us* pl = (const us*)p1;
        const int i = tid >> 1, ko = (tid & 1) * 16;
        const long long g = (long long)(row0 + i) * ld + k0 + ko;
        *(ushort8v*)&ldsH[i * LDSTRIDE + ko]     = *(const ushort8v*)&ph[g];
        *(ushort8v*)&ldsH[i * LDSTRIDE + ko + 8] = *(const ushort8v*)&ph[g + 8];
        *(ushort8v*)&ldsL[i * LDSTRIDE + ko]     = *(const ushort8v*)&pl[g];
        *(ushort8v*)&ldsL[i * LDSTRIDE + ko + 8] = *(const ushort8v*)&pl[g + 8];
    } else if constexpr (MODE == OPM_B16_ROW) {
        const us* ph = (const us*)p0;
        const int i = tid >> 1, ko = (tid & 1) * 16;
        const long long g = (long long)(row0 + i) * ld + k0 + ko;
        *(ushort8v*)&ldsH[i * LDSTRIDE + ko]     = *(const ushort8v*)&ph[g];
        *(ushort8v*)&ldsH[i * LDSTRIDE + ko + 8] = *(const ushort8v*)&ph[g + 8];
    } else if constexpr (MODE == OPM_F32_ROW) {
        const float* pf = (const float*)p0;
        const int i = tid >> 1, ko = (tid & 1) * 16;
        const long long g = (long long)(row0 + i) * ld + k0 + ko;
        us h16[16], l16[16];
        #pragma unroll
        for (int c = 0; c < 16; c += 4) {
            float4 v = *(const float4*)&pf[g + c];
            split_bf(v.x, h16[c+0], l16[c+0]); split_bf(v.y, h16[c+1], l16[c+1]);
            split_bf(v.z, h16[c+2], l16[c+2]); split_bf(v.w, h16[c+3], l16[c+3]);
        }
        *(ushort8v*)&ldsH[i * LDSTRIDE + ko]     = *(const ushort8v*)&h16[0];
        *(ushort8v*)&ldsH[i * LDSTRIDE + ko + 8] = *(const ushort8v*)&h16[8];
        *(ushort8v*)&ldsL[i * LDSTRIDE + ko]     = *(const ushort8v*)&l16[0];
        *(ushort8v*)&ldsL[i * LDSTRIDE + ko + 8] = *(const ushort8v*)&l16[8];
    } else if constexpr (MODE == OPM_F32_COL) {
        const float* pf = (const float*)p0;
        const int m = tid & 127, kh = (tid >> 7) * 16;
        const long long base = (long long)(k0 + kh) * ld + row0 + m;
        us vh[16], vl[16];
        #pragma unroll
        for (int kk = 0; kk < 16; ++kk)
            split_bf(pf[base + (long long)kk * ld], vh[kk], vl[kk]);
        *(ushort8v*)&ldsH[m * LDSTRIDE + kh]     = *(const ushort8v*)&vh[0];
        *(ushort8v*)&ldsH[m * LDSTRIDE + kh + 8] = *(const ushort8v*)&vh[8];
        *(ushort8v*)&ldsL[m * LDSTRIDE + kh]     = *(const ushort8v*)&vl[0];
        *(ushort8v*)&ldsL[m * LDSTRIDE + kh + 8] = *(const ushort8v*)&vl[8];
    } else if constexpr (MODE == OPM_B16_COL) {
        const us* ph = (const us*)p0;
        const int m = tid & 127, kh = (tid >> 7) * 16;
        const long long base = (long long)(k0 + kh) * ld + row0 + m;
        us v[16];
        #pragma unroll
        for (int kk = 0; kk < 16; ++kk)
            v[kk] = ph[base + (long long)kk * ld];
        *(ushort8v*)&ldsH[m * LDSTRIDE + kh]     = *(const ushort8v*)&v[0];
        *(ushort8v*)&ldsH[m * LDSTRIDE + kh + 8] = *(const ushort8v*)&v[8];
    } else if constexpr (MODE == OPM_WGT_COL) {
        // R7: weights transform fused into staging (was a 134 MB pass):
        // w = (sim - lo)/(hi - lo + eps), thresholded at SIGMA, bf16-rounded
        // exactly like the old weights_bf_k.
        const us* ph = (const us*)p0;
        const int m = tid & 127, kh = (tid >> 7) * 16;
        const float lo = wlo[row0 + m];
        const float inv = 1.0f / (whi[row0 + m] - lo + 1e-8f);
        const long long base = (long long)(k0 + kh) * ld + row0 + m;
        us v[16];
        #pragma unroll
        for (int kk = 0; kk < 16; ++kk) {
            const float w = (bf2f(ph[base + (long long)kk * ld]) - lo) * inv;
            v[kk] = (w < SIGMA) ? (us)0 : f2bf(w);
        }
        *(ushort8v*)&ldsH[m * LDSTRIDE + kh]     = *(const ushort8v*)&v[0];
        *(ushort8v*)&ldsH[m * LDSTRIDE + kh + 8] = *(const ushort8v*)&v[8];
    }
}

template<int AMODE, int BMODE, int OMODE, int EPI>
__global__ __launch_bounds__(256) void mfma_gemm(
    const void* A0, const void* A1, const void* B0, const void* B1,
    void* C0,
    int M, int N, int K, int lda, int ldb, int ldc,
    long long sA, long long sB, long long sC,
    const float* __restrict__ bias, const float* __restrict__ invm,
    const float* __restrict__ invn, float scale,
    const float* __restrict__ wlo, const float* __restrict__ whi)
{
    constexpr bool ASPL = (AMODE <= OPM_SPL_COL);
    constexpr bool BSPL = (BMODE <= OPM_SPL_COL);
    constexpr int ASZ = 128 * LDSTRIDE;
    __shared__ __align__(16) us Ah[ASZ];
    __shared__ __align__(16) us Al[ASPL ? ASZ : 8];
    __shared__ __align__(16) us Bh[ASZ];
    __shared__ __align__(16) us Bl[BSPL ? ASZ : 8];

    const int tid = threadIdx.x;
    const int w = tid >> 6, lane = tid & 63;
    const int quad = lane >> 4, l16 = lane & 15;
    const int m0 = blockIdx.x * 128, n0 = blockIdx.y * 128;
    const int b = blockIdx.z;

    const char* Ab0 = (const char*)A0 + (long long)b * sA;
    const char* Ab1 = A1 ? (const char*)A1 + (long long)b * sA : nullptr;
    const char* Bb0 = (const char*)B0 + (long long)b * sB;
    const char* Bb1 = B1 ? (const char*)B1 + (long long)b * sB : nullptr;
    const float* wloA = wlo ? wlo + (long long)b * M : nullptr;
    const float* whiA = whi ? whi + (long long)b * M : nullptr;

    floatx4 acc[2][8];
    #pragma unroll
    for (int mi = 0; mi < 2; ++mi)
        #pragma unroll
        for (int ni = 0; ni < 8; ++ni)
            acc[mi][ni] = (floatx4){0.f, 0.f, 0.f, 0.f};

    for (int k0 = 0; k0 < K; k0 += 32) {
        stage_tile<AMODE>(Ab0, Ab1, lda, m0, k0, Ah, Al, tid, wloA, whiA);
        stage_tile<BMODE>(Bb0, Bb1, ldb, n0, k0, Bh, Bl, tid, nullptr, nullptr);
        __syncthreads();

        short8v ah[2], al[2], bh[8], bl[8];
        #pragma unroll
        for (int mi = 0; mi < 2; ++mi) {
            const int r = (32 * w + 16 * mi + l16) * LDSTRIDE + quad * 8;
            ah[mi] = *(const short8v*)&Ah[r];
            if constexpr (ASPL) al[mi] = *(const short8v*)&Al[r];
        }
        #pragma unroll
        for (int ni = 0; ni < 8; ++ni) {
            const int r = (16 * ni + l16) * LDSTRIDE + quad * 8;
            bh[ni] = *(const short8v*)&Bh[r];
            if constexpr (BSPL) bl[ni] = *(const short8v*)&Bl[r];
        }
        #pragma unroll
        for (int mi = 0; mi < 2; ++mi)
            #pragma unroll
            for (int ni = 0; ni < 8; ++ni) {
                acc[mi][ni] = __builtin_amdgcn_mfma_f32_16x16x32_bf16(ah[mi], bh[ni], acc[mi][ni], 0, 0, 0);
                if constexpr (BSPL)
                    acc[mi][ni] = __builtin_amdgcn_mfma_f32_16x16x32_bf16(ah[mi], bl[ni], acc[mi][ni], 0, 0, 0);
                if constexpr (ASPL)
                    acc[mi][ni] = __builtin_amdgcn_mfma_f32_16x16x32_bf16(al[mi], bh[ni], acc[mi][ni], 0, 0, 0);
            }
        __syncthreads();
    }

    char* Cb0 = (char*)C0 + (long long)b * sC;
    #pragma unroll
    for (int mi = 0; mi < 2; ++mi)
        #pragma unroll
        for (int ni = 0; ni < 8; ++ni)
            #pragma unroll
            for (int r = 0; r < 4; ++r) {
                const int row = m0 + 32 * w + 16 * mi + quad * 4 + r;
                const int col = n0 + 16 * ni + l16;
                float v = acc[mi][ni][r];
                if constexpr (EPI == 1) v += bias[col];
                if constexpr (EPI == 2) v *= invm[b * M + row] * invn[b * N + col] * scale;
                const long long idx = (long long)row * ldc + col;
                if constexpr (OMODE == OUT_F32) ((float*)Cb0)[idx] = v;
                else                            ((us*)Cb0)[idx] = f2bf(v);
            }
}

// =====================  small kernels  =====================

__global__ __launch_bounds__(256) void convert_w_k(
    const float* Wv, const float* Wt, us* Wvh, us* Wvl, us* Wth, us* Wtl)
{
    const int i = blockIdx.x * 256 + threadIdx.x;
    split_bf(Wv[i], Wvh[i], Wvl[i]);
    split_bf(Wt[i], Wth[i], Wtl[i]);
}

__global__ __launch_bounds__(256) void mean_img_k(
    const float* __restrict__ img, float* __restrict__ mimg)
{
    const int row = blockIdx.x * 4 + (threadIdx.x >> 6);
    const int lane = threadIdx.x & 63;
    const float* p = img + (long long)row * 1024;
    float s = 0.f;
    #pragma unroll
    for (int c = 0; c < 4; ++c) {
        float4 v = *(const float4*)&p[(c * 64 + lane) * 4];
        s += v.x + v.y + v.z + v.w;
    }
    #pragma unroll
    for (int o = 32; o > 0; o >>= 1) s += __shfl_xor(s, o);
    if (lane == 0) mimg[row] = s * (1.0f / 1024.0f);
}

__global__ __launch_bounds__(256) void mean_text_s1(
    const float* __restrict__ text, float* __restrict__ part)
{
    const int b = blockIdx.x, ch = blockIdx.y, k = threadIdx.x;
    const float* p = text + ((long long)b * 512 + ch * 64) * 256 + k;
    float s = 0.f;
    for (int r = 0; r < 64; ++r) s += p[r * 256];
    part[(b * 8 + ch) * 256 + k] = s;
}
__global__ __launch_bounds__(256) void mean_text_s2(
    const float* __restrict__ part, float* __restrict__ mt)
{
    const int b = blockIdx.x, k = threadIdx.x;
    float s = 0.f;
    for (int c = 0; c < 8; ++c) s += part[(b * 8 + c) * 256 + k];
    mt[b * 256 + k] = s * (1.0f / 512.0f);
}

__global__ __launch_bounds__(256) void small_adapter_k(
    const float* __restrict__ x, const float* __restrict__ W,
    const float* __restrict__ bias, float* __restrict__ y)
{
    const int b = blockIdx.x, d = threadIdx.x;
    __shared__ float xs[256];
    xs[d] = x[b * 256 + d];
    __syncthreads();
    const float* w = W + (long long)d * 256;
    float s = bias[d];
    for (int k = 0; k < 256; ++k) s += xs[k] * w[k];
    y[b * 256 + d] = s;
}

// ---- parallelized global loss ----

__global__ __launch_bounds__(256) void inv_norm_f32_k(
    const float* __restrict__ x, float* __restrict__ inv)
{
    const int row = blockIdx.x * 4 + (threadIdx.x >> 6);
    const int lane = threadIdx.x & 63;
    float4 v = *(const float4*)&x[(long long)row * 256 + lane * 4];
    float s = v.x * v.x + v.y * v.y + v.z * v.z + v.w * v.w;
    #pragma unroll
    for (int o = 32; o > 0; o >>= 1) s += __shfl_xor(s, o);
    if (lane == 0) inv[row] = 1.0f / fmaxf(sqrtf(s), 1e-8f);
}

__global__ __launch_bounds__(256) void g_sim_k(
    const float* __restrict__ gi, const float* __restrict__ gt,
    const float* __restrict__ invI, const float* __restrict__ invT,
    float* __restrict__ gs)
{
    const int i = blockIdx.x, t = threadIdx.x;
    const int j = t >> 2, part = t & 3;
    __shared__ float a[256];
    a[t] = gi[i * 256 + t];
    __syncthreads();
    const float* bp = gt + (long long)j * 256 + part * 64;
    const float* ap = a + part * 64;
    float s = 0.f;
    #pragma unroll 16
    for (int k = 0; k < 64; ++k) s += ap[k] * bp[k];
    s += __shfl_xor(s, 1);
    s += __shfl_xor(s, 2);
    if (part == 0) gs[i * 64 + j] = s * invI[i] * invT[j] * TAU_INV;
}

__global__ __launch_bounds__(64) void g_lse_k(
    const float* __restrict__ gs, float* __restrict__ out)
{
    const int b = blockIdx.x, lane = threadIdx.x;
    const bool is_col = b >= 64;
    const int r = is_col ? b - 64 : b;
    const float v = is_col ? gs[lane * 64 + r] : gs[r * 64 + lane];
    float m = v;
    #pragma unroll
    for (int o = 32; o > 0; o >>= 1) m = fmaxf(m, __shfl_xor(m, o));
    float s = expf(v - m);
    #pragma unroll
    for (int o = 32; o > 0; o >>= 1) s += __shfl_xor(s, o);
    if (lane == 0)
        atomicAdd(out, ((m + logf(s)) - gs[r * 64 + r]) * (0.5f / 64.0f));
}

// minmax over p of bf16 sim, stage1: grid (128, 8); stage2: grid 128
__global__ __launch_bounds__(256) void minmax_s1(
    const us* __restrict__ simW, float* __restrict__ mnp, float* __restrict__ mxp)
{
    const int bx = blockIdx.x;
    const int b = bx >> 1, s = ((bx & 1) << 8) + threadIdx.x;
    const int ch = blockIdx.y;
    const us* p = simW + ((long long)b * 1024 + ch * 128) * 512 + s;
    float lo = 1e30f, hi = -1e30f;
    for (int r = 0; r < 128; ++r) {
        const float v = bf2f(p[(long long)r * 512]);
        lo = fminf(lo, v); hi = fmaxf(hi, v);
    }
    mnp[((long long)b * 8 + ch) * 512 + s] = lo;
    mxp[((long long)b * 8 + ch) * 512 + s] = hi;
}
__global__ __launch_bounds__(256) void minmax_s2(
    const float* __restrict__ mnp, const float* __restrict__ mxp,
    float* __restrict__ mn, float* __restrict__ mx)
{
    const int bx = blockIdx.x;
    const int b = bx >> 1, s = ((bx & 1) << 8) + threadIdx.x;
    float lo = 1e30f, hi = -1e30f;
    for (int c = 0; c < 8; ++c) {
        lo = fminf(lo, mnp[((long long)b * 8 + c) * 512 + s]);
        hi = fmaxf(hi, mxp[((long long)b * 8 + c) * 512 + s]);
    }
    mn[b * 512 + s] = lo;
    mx[b * 512 + s] = hi;
}

// inv L2 norm of 256-wide single-bf16 rows
__global__ __launch_bounds__(256) void inv_norm_b16_k(
    const us* __restrict__ x, float* __restrict__ inv)
{
    const int row = blockIdx.x * 4 + (threadIdx.x >> 6);
    const int lane = threadIdx.x & 63;
    ushort4 h = *(const ushort4*)&x[(long long)row * 256 + lane * 4];
    const float x0 = bf2f(h.x), x1 = bf2f(h.y), x2 = bf2f(h.z), x3 = bf2f(h.w);
    float s = x0 * x0 + x1 * x1 + x2 * x2 + x3 * x3;
    #pragma unroll
    for (int o = 32; o > 0; o >>= 1) s += __shfl_xor(s, o);
    if (lane == 0) inv[row] = 1.0f / fmaxf(sqrtf(s), 1e-8f);
}

// row logsumexp - diag: 512 blocks, 16 rows/wave, one atomic per block.
__global__ __launch_bounds__(256) void row_lse_k(
    const float* __restrict__ f, float* __restrict__ out)
{
    const int w = threadIdx.x >> 6, lane = threadIdx.x & 63;
    const int r0 = blockIdx.x * 64 + w * 16;
    float accum = 0.f;
    for (int rr = 0; rr < 16; ++rr) {
        const int r = r0 + rr;
        const float* p = f + (long long)r * SS;
        float4 v0 = *(const float4*)&p[lane * 8];
        float4 v1 = *(const float4*)&p[lane * 8 + 4];
        float vals[8] = {v0.x, v0.y, v0.z, v0.w, v1.x, v1.y, v1.z, v1.w};
        float m = vals[0];
        #pragma unroll
        for (int t = 1; t < 8; ++t) m = fmaxf(m, vals[t]);
        #pragma unroll
        for (int o = 32; o > 0; o >>= 1) m = fmaxf(m, __shfl_xor(m, o));
        float s = 0.f;
        #pragma unroll
        for (int t = 0; t < 8; ++t) s += expf(vals[t] - m);
        #pragma unroll
        for (int o = 32; o > 0; o >>= 1) s += __shfl_xor(s, o);
        accum += (m + logf(s)) - p[r & (SS - 1)];
    }
    __shared__ float red[4];
    if (lane == 0) red[w] = accum;
    __syncthreads();
    if (threadIdx.x == 0)
        atomicAdd(out, (red[0] + red[1] + red[2] + red[3]) * (0.5f / (64.0f * 512.0f)));
}

// two-stage column LSE
__global__ __launch_bounds__(256) void col_lse_s1(
    const float* __restrict__ f, float* __restrict__ pm, float* __restrict__ ps)
{
    const int b = blockIdx.x, ch = blockIdx.y;
    const float* base = f + (long long)b * SS * SS + (long long)ch * 64 * SS;
    const int c0 = threadIdx.x * 2;
    float m0 = -1e30f, m1 = -1e30f, s0 = 0.f, s1 = 0.f;
    #pragma unroll 4
    for (int r = 0; r < 64; ++r) {
        const float2 v = *(const float2*)&base[r * SS + c0];
        const float nm0 = fmaxf(m0, v.x);
        s0 = s0 * expf(m0 - nm0) + expf(v.x - nm0);
        m0 = nm0;
        const float nm1 = fmaxf(m1, v.y);
        s1 = s1 * expf(m1 - nm1) + expf(v.y - nm1);
        m1 = nm1;
    }
    const long long o = ((long long)b * 8 + ch) * SS + c0;
    *(float2*)&pm[o] = make_float2(m0, m1);
    *(float2*)&ps[o] = make_float2(s0, s1);
}
__global__ __launch_bounds__(256) void col_lse_s2(
    const float* __restrict__ pm, const float* __restrict__ ps,
    const float* __restrict__ f, float* __restrict__ out)
{
    const int b = blockIdx.x >> 1;
    const int j = ((blockIdx.x & 1) << 8) + threadIdx.x;
    float m = -1e30f, s = 0.f;
    #pragma unroll
    for (int c = 0; c < 8; ++c) {
        const long long o = ((long long)b * 8 + c) * SS + j;
        const float cm = pm[o], cs = ps[o];
        const float nm = fmaxf(m, cm);
        s = s * expf(m - nm) + cs * expf(cm - nm);
        m = nm;
    }
    const float contrib = (m + logf(s)) - f[(long long)b * SS * SS + (long long)j * SS + j];
    __shared__ float red[256];
    red[threadIdx.x] = contrib;
    __syncthreads();
    for (int w = 128; w > 0; w >>= 1) {
        if (threadIdx.x < w) red[threadIdx.x] += red[threadIdx.x + w];
        __syncthreads();
    }
    if (threadIdx.x == 0) atomicAdd(out, red[0] * (0.5f / (64.0f * 512.0f)));
}

extern "C" void kernel_launch(void* const* d_in, const int* in_sizes, int n_in,
                              void* d_out, int out_size, void* d_ws, size_t ws_size,
                              hipStream_t stream)
{
    const float* img  = (const float*)d_in[0];
    const float* text = (const float*)d_in[1];
    const float* Wv   = (const float*)d_in[2];
    const float* bv   = (const float*)d_in[3];
    const float* Wt   = (const float*)d_in[4];
    const float* bt   = (const float*)d_in[5];
    float* out = (float*)d_out;
    char* ws = (char*)d_ws;

    // R7 workspace: all activations single-bf16. Peak ~141 MB.
    us* patches = (us*)(ws + 0);              // 33,554,432 B
    us* tokens  = (us*)(ws + 33554432);       // 16,777,216 B
    us* simW    = (us*)(ws + 50331648);       // 67,108,864 B (bf16 sim)
    float* f_sim = (float*)(ws + 50331648);   // reuse after G6 (f32, 67 MB)
    us* lgve    = (us*)(ws + 117440512);      // 16,777,216 B
    char* st = ws + 134217728;
    float* mean_img  = (float*)(st + 0);
    float* mean_text = (float*)(st + 65536);
    float* mean_pat  = (float*)(st + 131072);
    float* mean_tok  = (float*)(st + 196608);
    float* g_img     = (float*)(st + 262144);
    float* g_txt     = (float*)(st + 327680);
    float* textpart  = (float*)(st + 393216);
    float* mnp       = (float*)(st + 917504);
    float* mxp       = (float*)(st + 1966080);
    float* mnv       = (float*)(st + 3014656);
    float* mxv       = (float*)(st + 3145728);
    float* inv_l     = (float*)(st + 3276800);
    float* inv_t     = (float*)(st + 3407872);
    us* Wvh = (us*)(st + 3538944);
    us* Wvl = (us*)(st + 3670016);
    us* Wth = (us*)(st + 3801088);
    us* Wtl = (us*)(st + 3932160);
    float* inv_gi  = (float*)(st + 4063232);
    float* inv_gt  = (float*)(st + 4063744);
    float* g_simbf = (float*)(st + 4064256);
    float* col_pm  = (float*)(st + 4194304);
    float* col_ps  = (float*)(st + 5242880);

    zero_out_k<<<1, 64, 0, stream>>>(out);
    convert_w_k<<<256, 256, 0, stream>>>(Wv, Wt, Wvh, Wvl, Wth, Wtl);

    // Global path (mean commutes with linear)
    mean_img_k<<<4096, 256, 0, stream>>>(img, mean_img);
    mean_text_s1<<<dim3(64, 8), 256, 0, stream>>>(text, textpart);
    mean_text_s2<<<64, 256, 0, stream>>>(textpart, mean_text);
    small_adapter_k<<<BB, 256, 0, stream>>>(mean_img, Wv, bv, mean_pat);
    small_adapter_k<<<BB, 256, 0, stream>>>(mean_pat, Wv, bv, g_img);
    small_adapter_k<<<BB, 256, 0, stream>>>(mean_text, Wt, bt, mean_tok);
    small_adapter_k<<<BB, 256, 0, stream>>>(mean_tok, Wt, bt, g_txt);
    inv_norm_f32_k<<<16, 256, 0, stream>>>(g_img, inv_gi);
    inv_norm_f32_k<<<16, 256, 0, stream>>>(g_txt, inv_gt);
    g_sim_k<<<64, 256, 0, stream>>>(g_img, g_txt, inv_gi, inv_gt, g_simbf);
    g_lse_k<<<128, 64, 0, stream>>>(g_simbf, out);

    // G1: patches = img.Wv + bv (split precision internally, bf16 out)
    mfma_gemm<OPM_F32_COL, OPM_SPL_ROW, OUT_B16, 1><<<dim3(8, 2, BB), 256, 0, stream>>>(
        img, nullptr, Wvh, Wvl, patches,
        1024, 256, 256, 1024, 256, 256,
        1048576LL, 0LL, 524288LL, bv, nullptr, nullptr, 0.f, nullptr, nullptr);

    // G2: tokens = text.Wt + bt
    mfma_gemm<OPM_F32_ROW, OPM_SPL_ROW, OUT_B16, 1><<<dim3(4, 2, BB), 256, 0, stream>>>(
        text, nullptr, Wth, Wtl, tokens,
        512, 256, 256, 256, 256, 256,
        524288LL, 0LL, 262144LL, bt, nullptr, nullptr, 0.f, nullptr, nullptr);

    // G4: sim = patches.tokens^T (single bf16, 1 mfma/pair)
    mfma_gemm<OPM_B16_ROW, OPM_B16_ROW, OUT_B16, 0><<<dim3(8, 4, BB), 256, 0, stream>>>(
        patches, nullptr, tokens, nullptr, simW,
        1024, 512, 256, 256, 256, 512,
        524288LL, 262144LL, 1048576LL, nullptr, nullptr, nullptr, 0.f, nullptr, nullptr);

    // min-max stats
    minmax_s1<<<dim3(128, 8), 256, 0, stream>>>(simW, mnp, mxp);
    minmax_s2<<<128, 256, 0, stream>>>(mnp, mxp, mnv, mxv);

    // G6: lgve = w.patches, weights transform FUSED into A staging
    mfma_gemm<OPM_WGT_COL, OPM_B16_COL, OUT_B16, 0><<<dim3(4, 2, BB), 256, 0, stream>>>(
        simW, nullptr, patches, nullptr, lgve,
        512, 256, 1024, 512, 256, 256,
        1048576LL, 524288LL, 262144LL, nullptr, nullptr, nullptr, 0.f, mnv, mxv);

    // inverse L2 norms (from the same bf16 tensors the GEMMs consume)
    inv_norm_b16_k<<<8192, 256, 0, stream>>>(lgve, inv_l);
    inv_norm_b16_k<<<8192, 256, 0, stream>>>(tokens, inv_t);

    // G8: f_sim = cos(lgve, tokens)/tau -> fp32
    mfma_gemm<OPM_B16_ROW, OPM_B16_ROW, OUT_F32, 2><<<dim3(4, 4, BB), 256, 0, stream>>>(
        lgve, nullptr, tokens, nullptr, f_sim,
        512, 512, 256, 256, 256, 512,
        262144LL, 262144LL, 1048576LL, nullptr, inv_l, inv_t, TAU_INV, nullptr, nullptr);

    // fine-grained symmetric CE
    row_lse_k<<<512, 256, 0, stream>>>(f_sim, out);
    col_lse_s1<<<dim3(BB, 8), 256, 0, stream>>>(f_sim, col_pm, col_ps);
    col_lse_s2<<<128, 256, 0, stream>>>(col_pm, col_ps, f_sim, out);
}